// Round 1
// baseline (2035.812 us; speedup 1.0000x reference)
//
#include <hip/hip_runtime.h>
#include <cstddef>

#define NSLOPE 0.2f

constexpr int NN = 50000;
constexpr int EE = 800000;
constexpr int GG = 64;
constexpr int SCAN_B = 1024;

// ---------------- CSR build (dst-sorted edge permutation) ----------------
__global__ void hist_kernel(const int* __restrict__ dst, int* __restrict__ hist, int E) {
  int e = blockIdx.x * blockDim.x + threadIdx.x;
  if (e < E) atomicAdd(&hist[dst[e]], 1);
}

__global__ void scan_block_kernel(const int* __restrict__ in, int* __restrict__ out,
                                  int* __restrict__ bsum, int n) {
  __shared__ int tmp[SCAN_B];
  int gid = blockIdx.x * SCAN_B + threadIdx.x;
  int v = (gid < n) ? in[gid] : 0;
  tmp[threadIdx.x] = v;
  __syncthreads();
  for (int off = 1; off < SCAN_B; off <<= 1) {
    int t = (threadIdx.x >= off) ? tmp[threadIdx.x - off] : 0;
    __syncthreads();
    tmp[threadIdx.x] += t;
    __syncthreads();
  }
  if (gid < n) out[gid] = tmp[threadIdx.x];
  if (threadIdx.x == SCAN_B - 1) bsum[blockIdx.x] = tmp[threadIdx.x];
}

__global__ void scan_totals_kernel(const int* __restrict__ bsum, int* __restrict__ boff, int nb) {
  if (blockIdx.x == 0 && threadIdx.x == 0) {
    int run = 0;
    for (int i = 0; i < nb; ++i) { boff[i] = run; run += bsum[i]; }
  }
}

__global__ void add_offsets_kernel(int* __restrict__ rowptr, const int* __restrict__ boff, int n) {
  int gid = blockIdx.x * SCAN_B + threadIdx.x;
  if (gid == 0) rowptr[0] = 0;
  if (gid < n) rowptr[1 + gid] += boff[blockIdx.x];
}

__global__ void copy_cursor_kernel(const int* __restrict__ rowptr, int* __restrict__ cursor, int n) {
  int i = blockIdx.x * blockDim.x + threadIdx.x;
  if (i < n) cursor[i] = rowptr[i];
}

__global__ void scatter_perm_kernel(const int* __restrict__ dst, int* __restrict__ cursor,
                                    int* __restrict__ perm, int E) {
  int e = blockIdx.x * blockDim.x + threadIdx.x;
  if (e < E) {
    int pos = atomicAdd(&cursor[dst[e]], 1);
    perm[pos] = e;
  }
}

// mean edge_attr per destination node (for self-loop fill_value='mean')
__global__ void mean_attr_kernel(const int* __restrict__ rowptr, const int* __restrict__ perm,
                                 const float* __restrict__ eattr, float* __restrict__ meanattr,
                                 int N) {
  int idx = blockIdx.x * blockDim.x + threadIdx.x;
  if (idx >= N * 16) return;
  int i = idx >> 4, k = idx & 15;
  int beg = rowptr[i], end = rowptr[i + 1];
  float acc = 0.f;
  for (int j = beg; j < end; ++j) acc += eattr[(size_t)perm[j] * 16 + k];
  int c = end - beg; if (c < 1) c = 1;
  meanattr[idx] = acc / (float)c;
}

// ---------------- fused dual GEMM: Y0 = X@W0+b0, Y1 = X@W1+b1 (K=128) ----------------
__global__ __launch_bounds__(256) void gemm_dual_kernel(
    const float* __restrict__ X,
    const float* __restrict__ W0, const float* __restrict__ b0, float* __restrict__ Y0,
    const float* __restrict__ W1, const float* __restrict__ b1, float* __restrict__ Y1,
    int M, int Nc) {
  constexpr int K = 128, BM = 128, BN = 128, BK = 16;
  __shared__ float As[BK][BM + 4];
  __shared__ float Bs[BK][BN];
  int nb = Nc >> 7;
  int half = blockIdx.y / nb;
  int cb = blockIdx.y % nb;
  const float* W = half ? W1 : W0;
  const float* bias = half ? b1 : b0;
  float* Y = half ? Y1 : Y0;
  int row0 = blockIdx.x * BM;
  int col0 = cb * BN;
  int tid = threadIdx.x;
  int tr = tid >> 4, tc = tid & 15;
  float acc[8][8];
#pragma unroll
  for (int i = 0; i < 8; ++i)
#pragma unroll
    for (int j = 0; j < 8; ++j) acc[i][j] = 0.f;

  for (int k0 = 0; k0 < K; k0 += BK) {
#pragma unroll
    for (int u = 0; u < 2; ++u) {
      int idx = tid + u * 256;
      int r = idx >> 2, c4 = (idx & 3) << 2;
      int row = row0 + r;
      float4 v = make_float4(0.f, 0.f, 0.f, 0.f);
      if (row < M) v = *reinterpret_cast<const float4*>(X + (size_t)row * K + k0 + c4);
      As[c4 + 0][r] = v.x; As[c4 + 1][r] = v.y; As[c4 + 2][r] = v.z; As[c4 + 3][r] = v.w;
    }
#pragma unroll
    for (int u = 0; u < 2; ++u) {
      int idx = tid + u * 256;
      int r = idx >> 5, c4 = (idx & 31) << 2;
      *reinterpret_cast<float4*>(&Bs[r][c4]) =
          *reinterpret_cast<const float4*>(W + (size_t)(k0 + r) * Nc + col0 + c4);
    }
    __syncthreads();
#pragma unroll
    for (int kk = 0; kk < BK; ++kk) {
      float a[8], b[8];
      *reinterpret_cast<float4*>(&a[0]) = *reinterpret_cast<const float4*>(&As[kk][tr * 8]);
      *reinterpret_cast<float4*>(&a[4]) = *reinterpret_cast<const float4*>(&As[kk][tr * 8 + 4]);
      *reinterpret_cast<float4*>(&b[0]) = *reinterpret_cast<const float4*>(&Bs[kk][tc * 8]);
      *reinterpret_cast<float4*>(&b[4]) = *reinterpret_cast<const float4*>(&Bs[kk][tc * 8 + 4]);
#pragma unroll
      for (int i = 0; i < 8; ++i)
#pragma unroll
        for (int j = 0; j < 8; ++j) acc[i][j] = fmaf(a[i], b[j], acc[i][j]);
    }
    __syncthreads();
  }
#pragma unroll
  for (int i = 0; i < 8; ++i) {
    int row = row0 + tr * 8 + i;
    if (row >= M) continue;
    float* yp = Y + (size_t)row * Nc + col0 + tc * 8;
    const float* bp = bias + col0 + tc * 8;
    float4 o0 = make_float4(acc[i][0] + bp[0], acc[i][1] + bp[1], acc[i][2] + bp[2], acc[i][3] + bp[3]);
    float4 o1 = make_float4(acc[i][4] + bp[4], acc[i][5] + bp[5], acc[i][6] + bp[6], acc[i][7] + bp[7]);
    *reinterpret_cast<float4*>(yp) = o0;
    *reinterpret_cast<float4*>(yp + 4) = o1;
  }
}

// ---------------- vector load/store helpers ----------------
template <int VPL>
__device__ __forceinline__ void loadv(const float* p, float* v) {
  if constexpr (VPL == 2) {
    float2 t = *reinterpret_cast<const float2*>(p);
    v[0] = t.x; v[1] = t.y;
  } else {
    float4 t = *reinterpret_cast<const float4*>(p);
    v[0] = t.x; v[1] = t.y; v[2] = t.z; v[3] = t.w;
  }
}
template <int VPL>
__device__ __forceinline__ void storev(float* p, const float* v) {
  if constexpr (VPL == 2) {
    *reinterpret_cast<float2*>(p) = make_float2(v[0], v[1]);
  } else {
    *reinterpret_cast<float4*>(p) = make_float4(v[0], v[1], v[2], v[3]);
  }
}

// ---------------- edge logits: one wave per edge (incl. self loops) ----------------
// lane l covers channels [l*VPL, (l+1)*VPL); head = lane/16 (4 heads)
template <int C>
__global__ __launch_bounds__(256) void edge_logits_kernel(
    const int* __restrict__ src, const int* __restrict__ dst,
    const float* __restrict__ eattr, const float* __restrict__ meanattr,
    const float* __restrict__ xl, const float* __restrict__ xr,
    const float* __restrict__ We,   // [16, C]
    const float* __restrict__ att,  // [C] (H*ch flat)
    float* __restrict__ logits,     // [E+N, 4]
    int E, int Ntot) {
  constexpr int VPL = C / 64;
  const int lane = threadIdx.x & 63;
  const int wave0 = blockIdx.x * (blockDim.x >> 6) + (threadIdx.x >> 6);
  const int nwaves = gridDim.x * (blockDim.x >> 6);

  float wreg[16][VPL];
  float areg[VPL];
#pragma unroll
  for (int k = 0; k < 16; ++k)
#pragma unroll
    for (int j = 0; j < VPL; ++j) wreg[k][j] = We[k * C + lane * VPL + j];
#pragma unroll
  for (int j = 0; j < VPL; ++j) areg[j] = att[lane * VPL + j];

  for (int e = wave0; e < Ntot; e += nwaves) {
    int s, d;
    const float* ap;
    if (e < E) {
      s = src[e]; d = dst[e]; ap = eattr + (size_t)e * 16;
    } else {
      int i = e - E; s = i; d = i; ap = meanattr + (size_t)i * 16;
    }
    float a[16];
#pragma unroll
    for (int k = 0; k < 16; ++k) a[k] = ap[k];
    float xv[VPL], rv[VPL];
    loadv<VPL>(xl + (size_t)s * C + lane * VPL, xv);
    loadv<VPL>(xr + (size_t)d * C + lane * VPL, rv);
    float part = 0.f;
#pragma unroll
    for (int j = 0; j < VPL; ++j) {
      float z = xv[j] + rv[j];
#pragma unroll
      for (int k = 0; k < 16; ++k) z = fmaf(a[k], wreg[k][j], z);
      z = (z > 0.f) ? z : NSLOPE * z;
      part = fmaf(z, areg[j], part);
    }
    part += __shfl_xor(part, 1);
    part += __shfl_xor(part, 2);
    part += __shfl_xor(part, 4);
    part += __shfl_xor(part, 8);
    if ((lane & 15) == 0) logits[(size_t)e * 4 + (lane >> 4)] = part;
  }
}

// ---------------- per-node softmax + aggregation: one wave per dst node ----------------
template <int C, bool FINAL>
__global__ __launch_bounds__(256) void node_agg_kernel(
    const int* __restrict__ src,
    const int* __restrict__ rowptr, const int* __restrict__ perm,
    const float* __restrict__ xl, const float* __restrict__ logits,
    const float* __restrict__ bias, float* __restrict__ hout,
    int E, int N) {
  constexpr int VPL = C / 64;
  const int lane = threadIdx.x & 63;
  const int h = lane >> 4;
  int d = blockIdx.x * (blockDim.x >> 6) + (threadIdx.x >> 6);
  if (d >= N) return;
  int beg = rowptr[d], end = rowptr[d + 1];

  // pass 1: per-head max (self loop included)
  float m = logits[((size_t)E + d) * 4 + h];
  for (int j = beg; j < end; ++j) {
    float lg = logits[(size_t)perm[j] * 4 + h];
    m = fmaxf(m, lg);
  }
  // pass 2: exp-sum + weighted accumulation
  float s = 0.f;
  float acc[VPL];
#pragma unroll
  for (int j = 0; j < VPL; ++j) acc[j] = 0.f;
  {
    float p = expf(logits[((size_t)E + d) * 4 + h] - m);
    s += p;
    float xv[VPL];
    loadv<VPL>(xl + (size_t)d * C + lane * VPL, xv);
#pragma unroll
    for (int j = 0; j < VPL; ++j) acc[j] = fmaf(p, xv[j], acc[j]);
  }
  for (int j = beg; j < end; ++j) {
    int e = perm[j];
    int sn = src[e];
    float p = expf(logits[(size_t)e * 4 + h] - m);
    s += p;
    float xv[VPL];
    loadv<VPL>(xl + (size_t)sn * C + lane * VPL, xv);
#pragma unroll
    for (int jj = 0; jj < VPL; ++jj) acc[jj] = fmaf(p, xv[jj], acc[jj]);
  }
  float inv = 1.f / (s + 1e-16f);
  if constexpr (!FINAL) {
    float res[VPL];
#pragma unroll
    for (int j = 0; j < VPL; ++j) {
      float v = acc[j] * inv + bias[lane * VPL + j];
      res[j] = v > 0.f ? v : 0.f;
    }
    storev<VPL>(hout + (size_t)d * C + lane * VPL, res);
  } else {
    // concat=False: mean over 4 heads, + bias, relu -> 64 features
    float v[VPL];
#pragma unroll
    for (int j = 0; j < VPL; ++j) v[j] = acc[j] * inv;
#pragma unroll
    for (int j = 0; j < VPL; ++j) {
      v[j] += __shfl_xor(v[j], 16);
      v[j] += __shfl_xor(v[j], 32);
    }
    if (lane < 16) {
      float res[VPL];
#pragma unroll
      for (int j = 0; j < VPL; ++j) {
        float val = 0.25f * v[j] + bias[lane * VPL + j];
        res[j] = val > 0.f ? val : 0.f;
      }
      storev<VPL>(hout + (size_t)d * 64 + lane * VPL, res);
    }
  }
}

// ---------------- global mean pool + final linear ----------------
__global__ void pool_kernel(const float* __restrict__ h3, const int* __restrict__ batch,
                            float* __restrict__ gsum, float* __restrict__ gcnt, int N) {
  int idx = blockIdx.x * blockDim.x + threadIdx.x;
  if (idx >= N * 64) return;
  int i = idx >> 6, f = idx & 63;
  int g = batch[i];
  atomicAdd(&gsum[(size_t)g * 64 + f], h3[idx]);
  if (f == 0) atomicAdd(&gcnt[g], 1.f);
}

__global__ void final_kernel(const float* __restrict__ gsum, const float* __restrict__ gcnt,
                             const float* __restrict__ Wlin, const float* __restrict__ blin,
                             float* __restrict__ out) {
  int idx = blockIdx.x * blockDim.x + threadIdx.x;
  if (idx >= GG * 16) return;
  int g = idx >> 4, o = idx & 15;
  float c = gcnt[g];
  c = c > 1.f ? c : 1.f;
  float inv = 1.f / c;
  float acc = blin[o];
  for (int f = 0; f < 64; ++f) acc = fmaf(gsum[(size_t)g * 64 + f] * inv, Wlin[f * 16 + o], acc);
  out[idx] = acc;
}

// ---------------- launch ----------------
extern "C" void kernel_launch(void* const* d_in, const int* in_sizes, int n_in,
                              void* d_out, int out_size, void* d_ws, size_t ws_size,
                              hipStream_t stream) {
  (void)in_sizes; (void)n_in; (void)out_size; (void)ws_size;
  const float* x     = (const float*)d_in[0];
  const int*   eidx  = (const int*)d_in[1];
  const int*   batch = (const int*)d_in[2];
  const float* eattr = (const float*)d_in[3];
  const float* Wl0 = (const float*)d_in[4];  const float* bl0 = (const float*)d_in[5];
  const float* Wr0 = (const float*)d_in[6];  const float* br0 = (const float*)d_in[7];
  const float* We0 = (const float*)d_in[8];  const float* att0 = (const float*)d_in[9];
  const float* bo0 = (const float*)d_in[10];
  const float* Wlh = (const float*)d_in[11]; const float* blh = (const float*)d_in[12];
  const float* Wrh = (const float*)d_in[13]; const float* brh = (const float*)d_in[14];
  const float* Weh = (const float*)d_in[15]; const float* atth = (const float*)d_in[16];
  const float* boh = (const float*)d_in[17];
  const float* Wlf = (const float*)d_in[18]; const float* blf = (const float*)d_in[19];
  const float* Wrf = (const float*)d_in[20]; const float* brf = (const float*)d_in[21];
  const float* Wef = (const float*)d_in[22]; const float* attf = (const float*)d_in[23];
  const float* bof = (const float*)d_in[24];
  const float* Wlin = (const float*)d_in[25]; const float* blin = (const float*)d_in[26];

  const int* src = eidx;
  const int* dst = eidx + EE;

  char* ws = (char*)d_ws;
  size_t off = 0;
  auto take = [&](size_t bytes) -> void* {
    void* p = ws + off;
    off += (bytes + 1023) & ~(size_t)1023;
    return p;
  };
  float* xl       = (float*)take((size_t)NN * 256 * 4);
  float* xr       = (float*)take((size_t)NN * 256 * 4);
  float* hbuf     = (float*)take((size_t)NN * 128 * 4);
  float* logits   = (float*)take((size_t)(EE + NN) * 4 * 4);
  float* meanattr = (float*)take((size_t)NN * 16 * 4);
  int* hist   = (int*)take((size_t)NN * 4);
  int* rowptr = (int*)take((size_t)(NN + 1) * 4);
  int* cursor = (int*)take((size_t)NN * 4);
  int* perm   = (int*)take((size_t)EE * 4);
  int* bsum   = (int*)take(256);
  int* boff   = (int*)take(256);
  float* gsum = (float*)take((size_t)GG * 64 * 4);
  float* gcnt = (float*)take((size_t)GG * 4);

  // ---- CSR by dst (dst fixed across layers; built every call) ----
  hipMemsetAsync(hist, 0, (size_t)NN * 4, stream);
  hipMemsetAsync(gsum, 0, (size_t)GG * 64 * 4, stream);
  hipMemsetAsync(gcnt, 0, (size_t)GG * 4, stream);
  hist_kernel<<<(EE + 255) / 256, 256, 0, stream>>>(dst, hist, EE);
  int nsb = (NN + SCAN_B - 1) / SCAN_B;
  scan_block_kernel<<<nsb, SCAN_B, 0, stream>>>(hist, rowptr + 1, bsum, NN);
  scan_totals_kernel<<<1, 64, 0, stream>>>(bsum, boff, nsb);
  add_offsets_kernel<<<nsb, SCAN_B, 0, stream>>>(rowptr, boff, NN);
  copy_cursor_kernel<<<(NN + 255) / 256, 256, 0, stream>>>(rowptr, cursor, NN);
  scatter_perm_kernel<<<(EE + 255) / 256, 256, 0, stream>>>(dst, cursor, perm, EE);
  mean_attr_kernel<<<(NN * 16 + 255) / 256, 256, 0, stream>>>(rowptr, perm, eattr, meanattr, NN);

  const int EL_BLOCKS = 2048;
  const int AGG_BLOCKS = (NN + 3) / 4;

  // ---- Layer 1 (C=128) ----
  dim3 g12((NN + 127) / 128, 2);
  gemm_dual_kernel<<<g12, 256, 0, stream>>>(x, Wl0, bl0, xl, Wr0, br0, xr, NN, 128);
  edge_logits_kernel<128><<<EL_BLOCKS, 256, 0, stream>>>(src, dst, eattr, meanattr, xl, xr,
                                                         We0, att0, logits, EE, EE + NN);
  node_agg_kernel<128, false><<<AGG_BLOCKS, 256, 0, stream>>>(src, rowptr, perm, xl, logits,
                                                              bo0, hbuf, EE, NN);
  // ---- Layer 2 (C=128) ----
  gemm_dual_kernel<<<g12, 256, 0, stream>>>(hbuf, Wlh, blh, xl, Wrh, brh, xr, NN, 128);
  edge_logits_kernel<128><<<EL_BLOCKS, 256, 0, stream>>>(src, dst, eattr, meanattr, xl, xr,
                                                         Weh, atth, logits, EE, EE + NN);
  node_agg_kernel<128, false><<<AGG_BLOCKS, 256, 0, stream>>>(src, rowptr, perm, xl, logits,
                                                              boh, hbuf, EE, NN);
  // ---- Layer 3 (C=256, mean over heads) ----
  dim3 g3((NN + 127) / 128, 4);
  gemm_dual_kernel<<<g3, 256, 0, stream>>>(hbuf, Wlf, blf, xl, Wrf, brf, xr, NN, 256);
  edge_logits_kernel<256><<<EL_BLOCKS, 256, 0, stream>>>(src, dst, eattr, meanattr, xl, xr,
                                                         Wef, attf, logits, EE, EE + NN);
  node_agg_kernel<256, true><<<AGG_BLOCKS, 256, 0, stream>>>(src, rowptr, perm, xl, logits,
                                                             bof, hbuf, EE, NN);
  // ---- pool + final linear ----
  pool_kernel<<<(NN * 64 + 255) / 256, 256, 0, stream>>>(hbuf, batch, gsum, gcnt, NN);
  final_kernel<<<4, 256, 0, stream>>>(gsum, gcnt, Wlin, blin, (float*)d_out);
}

// Round 2
// 1690.898 us; speedup vs baseline: 1.2040x; 1.2040x over previous
//
#include <hip/hip_runtime.h>
#include <cstddef>

#define NSLOPE 0.2f

constexpr int NN = 50000;
constexpr int EE = 800000;
constexpr int GG = 64;
constexpr int SCAN_B = 1024;

// ---------------- CSR build (dst-sorted edge permutation) ----------------
__global__ void hist_kernel(const int* __restrict__ dst, int* __restrict__ hist, int E) {
  int e = blockIdx.x * blockDim.x + threadIdx.x;
  if (e < E) atomicAdd(&hist[dst[e]], 1);
}

__global__ void scan_block_kernel(const int* __restrict__ in, int* __restrict__ out,
                                  int* __restrict__ bsum, int n) {
  __shared__ int tmp[SCAN_B];
  int gid = blockIdx.x * SCAN_B + threadIdx.x;
  int v = (gid < n) ? in[gid] : 0;
  tmp[threadIdx.x] = v;
  __syncthreads();
  for (int off = 1; off < SCAN_B; off <<= 1) {
    int t = (threadIdx.x >= off) ? tmp[threadIdx.x - off] : 0;
    __syncthreads();
    tmp[threadIdx.x] += t;
    __syncthreads();
  }
  if (gid < n) out[gid] = tmp[threadIdx.x];
  if (threadIdx.x == SCAN_B - 1) bsum[blockIdx.x] = tmp[threadIdx.x];
}

__global__ void scan_totals_kernel(const int* __restrict__ bsum, int* __restrict__ boff, int nb) {
  if (blockIdx.x == 0 && threadIdx.x == 0) {
    int run = 0;
    for (int i = 0; i < nb; ++i) { boff[i] = run; run += bsum[i]; }
  }
}

__global__ void add_offsets_kernel(int* __restrict__ rowptr, const int* __restrict__ boff, int n) {
  int gid = blockIdx.x * SCAN_B + threadIdx.x;
  if (gid == 0) rowptr[0] = 0;
  if (gid < n) rowptr[1 + gid] += boff[blockIdx.x];
}

__global__ void copy_cursor_kernel(const int* __restrict__ rowptr, int* __restrict__ cursor, int n) {
  int i = blockIdx.x * blockDim.x + threadIdx.x;
  if (i < n) cursor[i] = rowptr[i];
}

__global__ void scatter_perm_kernel(const int* __restrict__ dst, int* __restrict__ cursor,
                                    int* __restrict__ perm, int E) {
  int e = blockIdx.x * blockDim.x + threadIdx.x;
  if (e < E) {
    int pos = atomicAdd(&cursor[dst[e]], 1);
    perm[pos] = e;
  }
}

// mean edge_attr per destination node (for self-loop fill_value='mean')
__global__ void mean_attr_kernel(const int* __restrict__ rowptr, const int* __restrict__ perm,
                                 const float* __restrict__ eattr, float* __restrict__ meanattr,
                                 int N) {
  int idx = blockIdx.x * blockDim.x + threadIdx.x;
  if (idx >= N * 16) return;
  int i = idx >> 4, k = idx & 15;
  int beg = rowptr[i], end = rowptr[i + 1];
  float acc = 0.f;
  for (int j = beg; j < end; ++j) acc += eattr[(size_t)perm[j] * 16 + k];
  int c = end - beg; if (c < 1) c = 1;
  meanattr[idx] = acc / (float)c;
}

// ---------------- fused dual GEMM: Y0 = X@W0+b0, Y1 = X@W1+b1 (K=128) ----------------
__global__ __launch_bounds__(256) void gemm_dual_kernel(
    const float* __restrict__ X,
    const float* __restrict__ W0, const float* __restrict__ b0, float* __restrict__ Y0,
    const float* __restrict__ W1, const float* __restrict__ b1, float* __restrict__ Y1,
    int M, int Nc) {
  constexpr int K = 128, BM = 128, BN = 128, BK = 16;
  __shared__ float As[BK][BM + 4];
  __shared__ float Bs[BK][BN];
  int nb = Nc >> 7;
  int half = blockIdx.y / nb;
  int cb = blockIdx.y % nb;
  const float* W = half ? W1 : W0;
  const float* bias = half ? b1 : b0;
  float* Y = half ? Y1 : Y0;
  int row0 = blockIdx.x * BM;
  int col0 = cb * BN;
  int tid = threadIdx.x;
  int tr = tid >> 4, tc = tid & 15;
  float acc[8][8];
#pragma unroll
  for (int i = 0; i < 8; ++i)
#pragma unroll
    for (int j = 0; j < 8; ++j) acc[i][j] = 0.f;

  for (int k0 = 0; k0 < K; k0 += BK) {
#pragma unroll
    for (int u = 0; u < 2; ++u) {
      int idx = tid + u * 256;
      int r = idx >> 2, c4 = (idx & 3) << 2;
      int row = row0 + r;
      float4 v = make_float4(0.f, 0.f, 0.f, 0.f);
      if (row < M) v = *reinterpret_cast<const float4*>(X + (size_t)row * K + k0 + c4);
      As[c4 + 0][r] = v.x; As[c4 + 1][r] = v.y; As[c4 + 2][r] = v.z; As[c4 + 3][r] = v.w;
    }
#pragma unroll
    for (int u = 0; u < 2; ++u) {
      int idx = tid + u * 256;
      int r = idx >> 5, c4 = (idx & 31) << 2;
      *reinterpret_cast<float4*>(&Bs[r][c4]) =
          *reinterpret_cast<const float4*>(W + (size_t)(k0 + r) * Nc + col0 + c4);
    }
    __syncthreads();
#pragma unroll
    for (int kk = 0; kk < BK; ++kk) {
      float a[8], b[8];
      *reinterpret_cast<float4*>(&a[0]) = *reinterpret_cast<const float4*>(&As[kk][tr * 8]);
      *reinterpret_cast<float4*>(&a[4]) = *reinterpret_cast<const float4*>(&As[kk][tr * 8 + 4]);
      *reinterpret_cast<float4*>(&b[0]) = *reinterpret_cast<const float4*>(&Bs[kk][tc * 8]);
      *reinterpret_cast<float4*>(&b[4]) = *reinterpret_cast<const float4*>(&Bs[kk][tc * 8 + 4]);
#pragma unroll
      for (int i = 0; i < 8; ++i)
#pragma unroll
        for (int j = 0; j < 8; ++j) acc[i][j] = fmaf(a[i], b[j], acc[i][j]);
    }
    __syncthreads();
  }
#pragma unroll
  for (int i = 0; i < 8; ++i) {
    int row = row0 + tr * 8 + i;
    if (row >= M) continue;
    float* yp = Y + (size_t)row * Nc + col0 + tc * 8;
    const float* bp = bias + col0 + tc * 8;
    float4 o0 = make_float4(acc[i][0] + bp[0], acc[i][1] + bp[1], acc[i][2] + bp[2], acc[i][3] + bp[3]);
    float4 o1 = make_float4(acc[i][4] + bp[4], acc[i][5] + bp[5], acc[i][6] + bp[6], acc[i][7] + bp[7]);
    *reinterpret_cast<float4*>(yp) = o0;
    *reinterpret_cast<float4*>(yp + 4) = o1;
  }
}

// ---------------- vector load/store helpers ----------------
template <int VPL>
__device__ __forceinline__ void loadv(const float* p, float* v) {
  if constexpr (VPL == 2) {
    float2 t = *reinterpret_cast<const float2*>(p);
    v[0] = t.x; v[1] = t.y;
  } else {
    float4 t = *reinterpret_cast<const float4*>(p);
    v[0] = t.x; v[1] = t.y; v[2] = t.z; v[3] = t.w;
  }
}
template <int VPL>
__device__ __forceinline__ void storev(float* p, const float* v) {
  if constexpr (VPL == 2) {
    *reinterpret_cast<float2*>(p) = make_float2(v[0], v[1]);
  } else {
    *reinterpret_cast<float4*>(p) = make_float4(v[0], v[1], v[2], v[3]);
  }
}

// ---------------- edge logits: one wave per edge (incl. self loops) ----------------
// lane l covers channels [l*VPL, (l+1)*VPL); head = lane/16 (4 heads)
template <int C>
__global__ __launch_bounds__(256) void edge_logits_kernel(
    const int* __restrict__ src, const int* __restrict__ dst,
    const float* __restrict__ eattr, const float* __restrict__ meanattr,
    const float* __restrict__ xl, const float* __restrict__ xr,
    const float* __restrict__ We,   // [16, C]
    const float* __restrict__ att,  // [C] (H*ch flat)
    float* __restrict__ logits,     // [E+N, 4]
    int E, int Ntot) {
  constexpr int VPL = C / 64;
  const int lane = threadIdx.x & 63;
  const int wave0 = blockIdx.x * (blockDim.x >> 6) + (threadIdx.x >> 6);
  const int nwaves = gridDim.x * (blockDim.x >> 6);

  float wreg[16][VPL];
  float areg[VPL];
#pragma unroll
  for (int k = 0; k < 16; ++k)
#pragma unroll
    for (int j = 0; j < VPL; ++j) wreg[k][j] = We[k * C + lane * VPL + j];
#pragma unroll
  for (int j = 0; j < VPL; ++j) areg[j] = att[lane * VPL + j];

  for (int e = wave0; e < Ntot; e += nwaves) {
    int s, d;
    const float* ap;
    if (e < E) {
      s = src[e]; d = dst[e]; ap = eattr + (size_t)e * 16;
    } else {
      int i = e - E; s = i; d = i; ap = meanattr + (size_t)i * 16;
    }
    float a[16];
#pragma unroll
    for (int k = 0; k < 16; ++k) a[k] = ap[k];
    float xv[VPL], rv[VPL];
    loadv<VPL>(xl + (size_t)s * C + lane * VPL, xv);
    loadv<VPL>(xr + (size_t)d * C + lane * VPL, rv);
    float part = 0.f;
#pragma unroll
    for (int j = 0; j < VPL; ++j) {
      float z = xv[j] + rv[j];
#pragma unroll
      for (int k = 0; k < 16; ++k) z = fmaf(a[k], wreg[k][j], z);
      z = (z > 0.f) ? z : NSLOPE * z;
      part = fmaf(z, areg[j], part);
    }
    part += __shfl_xor(part, 1);
    part += __shfl_xor(part, 2);
    part += __shfl_xor(part, 4);
    part += __shfl_xor(part, 8);
    if ((lane & 15) == 0) logits[(size_t)e * 4 + (lane >> 4)] = part;
  }
}

// ---------------- per-node softmax + aggregation: one wave per dst node ----------------
template <int C, bool FINAL>
__global__ __launch_bounds__(256) void node_agg_kernel(
    const int* __restrict__ src,
    const int* __restrict__ rowptr, const int* __restrict__ perm,
    const float* __restrict__ xl, const float* __restrict__ logits,
    const float* __restrict__ bias, float* __restrict__ hout,
    int E, int N) {
  constexpr int VPL = C / 64;
  const int lane = threadIdx.x & 63;
  const int h = lane >> 4;
  int d = blockIdx.x * (blockDim.x >> 6) + (threadIdx.x >> 6);
  if (d >= N) return;
  int beg = rowptr[d], end = rowptr[d + 1];

  // pass 1: per-head max (self loop included)
  float m = logits[((size_t)E + d) * 4 + h];
  for (int j = beg; j < end; ++j) {
    float lg = logits[(size_t)perm[j] * 4 + h];
    m = fmaxf(m, lg);
  }
  // pass 2: exp-sum + weighted accumulation
  float s = 0.f;
  float acc[VPL];
#pragma unroll
  for (int j = 0; j < VPL; ++j) acc[j] = 0.f;
  {
    float p = expf(logits[((size_t)E + d) * 4 + h] - m);
    s += p;
    float xv[VPL];
    loadv<VPL>(xl + (size_t)d * C + lane * VPL, xv);
#pragma unroll
    for (int j = 0; j < VPL; ++j) acc[j] = fmaf(p, xv[j], acc[j]);
  }
  for (int j = beg; j < end; ++j) {
    int e = perm[j];
    int sn = src[e];
    float p = expf(logits[(size_t)e * 4 + h] - m);
    s += p;
    float xv[VPL];
    loadv<VPL>(xl + (size_t)sn * C + lane * VPL, xv);
#pragma unroll
    for (int jj = 0; jj < VPL; ++jj) acc[jj] = fmaf(p, xv[jj], acc[jj]);
  }
  float inv = 1.f / (s + 1e-16f);
  if constexpr (!FINAL) {
    float res[VPL];
#pragma unroll
    for (int j = 0; j < VPL; ++j) {
      float v = acc[j] * inv + bias[lane * VPL + j];
      res[j] = v > 0.f ? v : 0.f;
    }
    storev<VPL>(hout + (size_t)d * C + lane * VPL, res);
  } else {
    // concat=False: mean over 4 heads, + bias, relu -> 64 features
    float v[VPL];
#pragma unroll
    for (int j = 0; j < VPL; ++j) v[j] = acc[j] * inv;
#pragma unroll
    for (int j = 0; j < VPL; ++j) {
      v[j] += __shfl_xor(v[j], 16);
      v[j] += __shfl_xor(v[j], 32);
    }
    if (lane < 16) {
      float res[VPL];
#pragma unroll
      for (int j = 0; j < VPL; ++j) {
        float val = 0.25f * v[j] + bias[lane * VPL + j];
        res[j] = val > 0.f ? val : 0.f;
      }
      storev<VPL>(hout + (size_t)d * 64 + lane * VPL, res);
    }
  }
}

// ---------------- global mean pool: segmented reduction (batch is SORTED) ----------------
// One wave per contiguous node chunk; lane = feature (64 feats). Register
// accumulate while graph id unchanged; flush atomics only at graph boundaries.
__global__ __launch_bounds__(256) void pool_kernel(
    const float* __restrict__ h3, const int* __restrict__ batch,
    float* __restrict__ gsum, float* __restrict__ gcnt, int N) {
  const int lane = threadIdx.x & 63;
  const int w = blockIdx.x * (blockDim.x >> 6) + (threadIdx.x >> 6);
  const int nw = gridDim.x * (blockDim.x >> 6);
  const int chunk = (N + nw - 1) / nw;
  int i0 = w * chunk;
  int i1 = i0 + chunk; if (i1 > N) i1 = N;
  if (i0 >= i1) return;
  int cur = batch[i0];
  float acc = 0.f;
  int cnt = 0;
  for (int i = i0; i < i1; ++i) {
    int g = batch[i];
    if (g != cur) {
      atomicAdd(&gsum[(size_t)cur * 64 + lane], acc);
      if (lane == 0) atomicAdd(&gcnt[cur], (float)cnt);
      acc = 0.f; cnt = 0; cur = g;
    }
    acc += h3[(size_t)i * 64 + lane];
    ++cnt;
  }
  atomicAdd(&gsum[(size_t)cur * 64 + lane], acc);
  if (lane == 0) atomicAdd(&gcnt[cur], (float)cnt);
}

__global__ void final_kernel(const float* __restrict__ gsum, const float* __restrict__ gcnt,
                             const float* __restrict__ Wlin, const float* __restrict__ blin,
                             float* __restrict__ out) {
  int idx = blockIdx.x * blockDim.x + threadIdx.x;
  if (idx >= GG * 16) return;
  int g = idx >> 4, o = idx & 15;
  float c = gcnt[g];
  c = c > 1.f ? c : 1.f;
  float inv = 1.f / c;
  float acc = blin[o];
  for (int f = 0; f < 64; ++f) acc = fmaf(gsum[(size_t)g * 64 + f] * inv, Wlin[f * 16 + o], acc);
  out[idx] = acc;
}

// ---------------- launch ----------------
extern "C" void kernel_launch(void* const* d_in, const int* in_sizes, int n_in,
                              void* d_out, int out_size, void* d_ws, size_t ws_size,
                              hipStream_t stream) {
  (void)in_sizes; (void)n_in; (void)out_size; (void)ws_size;
  const float* x     = (const float*)d_in[0];
  const int*   eidx  = (const int*)d_in[1];
  const int*   batch = (const int*)d_in[2];
  const float* eattr = (const float*)d_in[3];
  const float* Wl0 = (const float*)d_in[4];  const float* bl0 = (const float*)d_in[5];
  const float* Wr0 = (const float*)d_in[6];  const float* br0 = (const float*)d_in[7];
  const float* We0 = (const float*)d_in[8];  const float* att0 = (const float*)d_in[9];
  const float* bo0 = (const float*)d_in[10];
  const float* Wlh = (const float*)d_in[11]; const float* blh = (const float*)d_in[12];
  const float* Wrh = (const float*)d_in[13]; const float* brh = (const float*)d_in[14];
  const float* Weh = (const float*)d_in[15]; const float* atth = (const float*)d_in[16];
  const float* boh = (const float*)d_in[17];
  const float* Wlf = (const float*)d_in[18]; const float* blf = (const float*)d_in[19];
  const float* Wrf = (const float*)d_in[20]; const float* brf = (const float*)d_in[21];
  const float* Wef = (const float*)d_in[22]; const float* attf = (const float*)d_in[23];
  const float* bof = (const float*)d_in[24];
  const float* Wlin = (const float*)d_in[25]; const float* blin = (const float*)d_in[26];

  const int* src = eidx;
  const int* dst = eidx + EE;

  char* ws = (char*)d_ws;
  size_t off = 0;
  auto take = [&](size_t bytes) -> void* {
    void* p = ws + off;
    off += (bytes + 1023) & ~(size_t)1023;
    return p;
  };
  float* xl       = (float*)take((size_t)NN * 256 * 4);
  float* xr       = (float*)take((size_t)NN * 256 * 4);
  float* hbuf     = (float*)take((size_t)NN * 128 * 4);
  float* logits   = (float*)take((size_t)(EE + NN) * 4 * 4);
  float* meanattr = (float*)take((size_t)NN * 16 * 4);
  int* hist   = (int*)take((size_t)NN * 4);
  int* rowptr = (int*)take((size_t)(NN + 1) * 4);
  int* cursor = (int*)take((size_t)NN * 4);
  int* perm   = (int*)take((size_t)EE * 4);
  int* bsum   = (int*)take(256);
  int* boff   = (int*)take(256);
  float* gsum = (float*)take((size_t)GG * 64 * 4);
  float* gcnt = (float*)take((size_t)GG * 4);

  // ---- CSR by dst (dst fixed across layers; built every call) ----
  hipMemsetAsync(hist, 0, (size_t)NN * 4, stream);
  hipMemsetAsync(gsum, 0, (size_t)GG * 64 * 4, stream);
  hipMemsetAsync(gcnt, 0, (size_t)GG * 4, stream);
  hist_kernel<<<(EE + 255) / 256, 256, 0, stream>>>(dst, hist, EE);
  int nsb = (NN + SCAN_B - 1) / SCAN_B;
  scan_block_kernel<<<nsb, SCAN_B, 0, stream>>>(hist, rowptr + 1, bsum, NN);
  scan_totals_kernel<<<1, 64, 0, stream>>>(bsum, boff, nsb);
  add_offsets_kernel<<<nsb, SCAN_B, 0, stream>>>(rowptr, boff, NN);
  copy_cursor_kernel<<<(NN + 255) / 256, 256, 0, stream>>>(rowptr, cursor, NN);
  scatter_perm_kernel<<<(EE + 255) / 256, 256, 0, stream>>>(dst, cursor, perm, EE);
  mean_attr_kernel<<<(NN * 16 + 255) / 256, 256, 0, stream>>>(rowptr, perm, eattr, meanattr, NN);

  const int EL_BLOCKS = 2048;
  const int AGG_BLOCKS = (NN + 3) / 4;

  // ---- Layer 1 (C=128) ----
  dim3 g12((NN + 127) / 128, 2);
  gemm_dual_kernel<<<g12, 256, 0, stream>>>(x, Wl0, bl0, xl, Wr0, br0, xr, NN, 128);
  edge_logits_kernel<128><<<EL_BLOCKS, 256, 0, stream>>>(src, dst, eattr, meanattr, xl, xr,
                                                         We0, att0, logits, EE, EE + NN);
  node_agg_kernel<128, false><<<AGG_BLOCKS, 256, 0, stream>>>(src, rowptr, perm, xl, logits,
                                                              bo0, hbuf, EE, NN);
  // ---- Layer 2 (C=128) ----
  gemm_dual_kernel<<<g12, 256, 0, stream>>>(hbuf, Wlh, blh, xl, Wrh, brh, xr, NN, 128);
  edge_logits_kernel<128><<<EL_BLOCKS, 256, 0, stream>>>(src, dst, eattr, meanattr, xl, xr,
                                                         Weh, atth, logits, EE, EE + NN);
  node_agg_kernel<128, false><<<AGG_BLOCKS, 256, 0, stream>>>(src, rowptr, perm, xl, logits,
                                                              boh, hbuf, EE, NN);
  // ---- Layer 3 (C=256, mean over heads) ----
  dim3 g3((NN + 127) / 128, 4);
  gemm_dual_kernel<<<g3, 256, 0, stream>>>(hbuf, Wlf, blf, xl, Wrf, brf, xr, NN, 256);
  edge_logits_kernel<256><<<EL_BLOCKS, 256, 0, stream>>>(src, dst, eattr, meanattr, xl, xr,
                                                         Wef, attf, logits, EE, EE + NN);
  node_agg_kernel<256, true><<<AGG_BLOCKS, 256, 0, stream>>>(src, rowptr, perm, xl, logits,
                                                             bof, hbuf, EE, NN);
  // ---- pool + final linear ----
  pool_kernel<<<128, 256, 0, stream>>>(hbuf, batch, gsum, gcnt, NN);
  final_kernel<<<4, 256, 0, stream>>>(gsum, gcnt, Wlin, blin, (float*)d_out);
}

// Round 3
// 1038.673 us; speedup vs baseline: 1.9600x; 1.6279x over previous
//
#include <hip/hip_runtime.h>
#include <cstddef>

#define NSLOPE 0.2f

constexpr int NN = 50000;
constexpr int EE = 800000;
constexpr int GG = 64;
constexpr int SCAN_B = 1024;

// ---------------- CSR build (dst-sorted edge permutation) ----------------
__global__ void hist_kernel(const int* __restrict__ dst, int* __restrict__ hist, int E) {
  int e = blockIdx.x * blockDim.x + threadIdx.x;
  if (e < E) atomicAdd(&hist[dst[e]], 1);
}

__global__ void scan_block_kernel(const int* __restrict__ in, int* __restrict__ out,
                                  int* __restrict__ bsum, int n) {
  __shared__ int tmp[SCAN_B];
  int gid = blockIdx.x * SCAN_B + threadIdx.x;
  int v = (gid < n) ? in[gid] : 0;
  tmp[threadIdx.x] = v;
  __syncthreads();
  for (int off = 1; off < SCAN_B; off <<= 1) {
    int t = (threadIdx.x >= off) ? tmp[threadIdx.x - off] : 0;
    __syncthreads();
    tmp[threadIdx.x] += t;
    __syncthreads();
  }
  if (gid < n) out[gid] = tmp[threadIdx.x];
  if (threadIdx.x == SCAN_B - 1) bsum[blockIdx.x] = tmp[threadIdx.x];
}

__global__ void scan_totals_kernel(const int* __restrict__ bsum, int* __restrict__ boff, int nb) {
  if (blockIdx.x == 0 && threadIdx.x == 0) {
    int run = 0;
    for (int i = 0; i < nb; ++i) { boff[i] = run; run += bsum[i]; }
  }
}

__global__ void add_offsets_kernel(int* __restrict__ rowptr, const int* __restrict__ boff, int n) {
  int gid = blockIdx.x * SCAN_B + threadIdx.x;
  if (gid == 0) rowptr[0] = 0;
  if (gid < n) rowptr[1 + gid] += boff[blockIdx.x];
}

__global__ void copy_cursor_kernel(const int* __restrict__ rowptr, int* __restrict__ cursor, int n) {
  int i = blockIdx.x * blockDim.x + threadIdx.x;
  if (i < n) cursor[i] = rowptr[i];
}

__global__ void scatter_perm_kernel(const int* __restrict__ dst, int* __restrict__ cursor,
                                    int* __restrict__ perm, int E) {
  int e = blockIdx.x * blockDim.x + threadIdx.x;
  if (e < E) {
    int pos = atomicAdd(&cursor[dst[e]], 1);
    perm[pos] = e;
  }
}

// permute src + eattr into dst-sorted order so the hot loop reads sequentially
__global__ void permute_kernel(const int* __restrict__ perm, const int* __restrict__ src,
                               const float* __restrict__ eattr,
                               int* __restrict__ srcp, float* __restrict__ eap, int E) {
  int j = blockIdx.x * blockDim.x + threadIdx.x;
  if (j >= E) return;
  int e = perm[j];
  srcp[j] = src[e];
  const float4* a = reinterpret_cast<const float4*>(eattr + (size_t)e * 16);
  float4* b = reinterpret_cast<float4*>(eap + (size_t)j * 16);
  b[0] = a[0]; b[1] = a[1]; b[2] = a[2]; b[3] = a[3];
}

// ---------------- fused dual GEMM: Y0 = X@W0+b0, Y1 = X@W1+b1 (K=128) ----------------
__global__ __launch_bounds__(256) void gemm_dual_kernel(
    const float* __restrict__ X,
    const float* __restrict__ W0, const float* __restrict__ b0, float* __restrict__ Y0,
    const float* __restrict__ W1, const float* __restrict__ b1, float* __restrict__ Y1,
    int M, int Nc) {
  constexpr int K = 128, BM = 128, BN = 128, BK = 16;
  __shared__ float As[BK][BM + 4];
  __shared__ float Bs[BK][BN];
  int nb = Nc >> 7;
  int half = blockIdx.y / nb;
  int cb = blockIdx.y % nb;
  const float* W = half ? W1 : W0;
  const float* bias = half ? b1 : b0;
  float* Y = half ? Y1 : Y0;
  int row0 = blockIdx.x * BM;
  int col0 = cb * BN;
  int tid = threadIdx.x;
  int tr = tid >> 4, tc = tid & 15;
  float acc[8][8];
#pragma unroll
  for (int i = 0; i < 8; ++i)
#pragma unroll
    for (int j = 0; j < 8; ++j) acc[i][j] = 0.f;

  for (int k0 = 0; k0 < K; k0 += BK) {
#pragma unroll
    for (int u = 0; u < 2; ++u) {
      int idx = tid + u * 256;
      int r = idx >> 2, c4 = (idx & 3) << 2;
      int row = row0 + r;
      float4 v = make_float4(0.f, 0.f, 0.f, 0.f);
      if (row < M) v = *reinterpret_cast<const float4*>(X + (size_t)row * K + k0 + c4);
      As[c4 + 0][r] = v.x; As[c4 + 1][r] = v.y; As[c4 + 2][r] = v.z; As[c4 + 3][r] = v.w;
    }
#pragma unroll
    for (int u = 0; u < 2; ++u) {
      int idx = tid + u * 256;
      int r = idx >> 5, c4 = (idx & 31) << 2;
      *reinterpret_cast<float4*>(&Bs[r][c4]) =
          *reinterpret_cast<const float4*>(W + (size_t)(k0 + r) * Nc + col0 + c4);
    }
    __syncthreads();
#pragma unroll
    for (int kk = 0; kk < BK; ++kk) {
      float a[8], b[8];
      *reinterpret_cast<float4*>(&a[0]) = *reinterpret_cast<const float4*>(&As[kk][tr * 8]);
      *reinterpret_cast<float4*>(&a[4]) = *reinterpret_cast<const float4*>(&As[kk][tr * 8 + 4]);
      *reinterpret_cast<float4*>(&b[0]) = *reinterpret_cast<const float4*>(&Bs[kk][tc * 8]);
      *reinterpret_cast<float4*>(&b[4]) = *reinterpret_cast<const float4*>(&Bs[kk][tc * 8 + 4]);
#pragma unroll
      for (int i = 0; i < 8; ++i)
#pragma unroll
        for (int j = 0; j < 8; ++j) acc[i][j] = fmaf(a[i], b[j], acc[i][j]);
    }
    __syncthreads();
  }
#pragma unroll
  for (int i = 0; i < 8; ++i) {
    int row = row0 + tr * 8 + i;
    if (row >= M) continue;
    float* yp = Y + (size_t)row * Nc + col0 + tc * 8;
    const float* bp = bias + col0 + tc * 8;
    float4 o0 = make_float4(acc[i][0] + bp[0], acc[i][1] + bp[1], acc[i][2] + bp[2], acc[i][3] + bp[3]);
    float4 o1 = make_float4(acc[i][4] + bp[4], acc[i][5] + bp[5], acc[i][6] + bp[6], acc[i][7] + bp[7]);
    *reinterpret_cast<float4*>(yp) = o0;
    *reinterpret_cast<float4*>(yp + 4) = o1;
  }
}

// ---------------- vector load/store helpers ----------------
template <int VPL>
__device__ __forceinline__ void loadv(const float* p, float* v) {
  if constexpr (VPL == 2) {
    float2 t = *reinterpret_cast<const float2*>(p);
    v[0] = t.x; v[1] = t.y;
  } else {
    float4 t = *reinterpret_cast<const float4*>(p);
    v[0] = t.x; v[1] = t.y; v[2] = t.z; v[3] = t.w;
  }
}
template <int VPL>
__device__ __forceinline__ void storev(float* p, const float* v) {
  if constexpr (VPL == 2) {
    *reinterpret_cast<float2*>(p) = make_float2(v[0], v[1]);
  } else {
    *reinterpret_cast<float4*>(p) = make_float4(v[0], v[1], v[2], v[3]);
  }
}

// one online-softmax edge update; the gathered xl row is reused for accumulation
template <int VPL, int C>
__device__ __forceinline__ void edge_update(
    const float* __restrict__ xl, int sn, int lane,
    const float* rv, const float (*wreg)[VPL], const float* areg,
    const float* ea, float& m, float& s, float* acc) {
  float xv[VPL];
  loadv<VPL>(xl + (size_t)sn * C + lane * VPL, xv);
  float part = 0.f;
#pragma unroll
  for (int j = 0; j < VPL; ++j) {
    float z = xv[j] + rv[j];
#pragma unroll
    for (int k = 0; k < 16; ++k) z = fmaf(ea[k], wreg[k][j], z);
    z = (z > 0.f) ? z : NSLOPE * z;
    part = fmaf(z, areg[j], part);
  }
  // butterfly over the 16 lanes of this head -> every lane holds the logit
  part += __shfl_xor(part, 1);
  part += __shfl_xor(part, 2);
  part += __shfl_xor(part, 4);
  part += __shfl_xor(part, 8);
  float newm = fmaxf(m, part);
  float sc = __expf(m - newm);  // 0 when m == -inf
  float p = __expf(part - newm);
  s = fmaf(s, sc, p);
#pragma unroll
  for (int j = 0; j < VPL; ++j) acc[j] = fmaf(acc[j], sc, p * xv[j]);
  m = newm;
}

// ---------------- fused GATv2 edge+softmax+aggregate: one wave per dst ----------------
template <int C, bool FINAL>
__global__ __launch_bounds__(256) void gat_fused_kernel(
    const int* __restrict__ rowptr,
    const int* __restrict__ srcp, const float* __restrict__ eap,  // permuted (optional)
    const int* __restrict__ perm, const int* __restrict__ src,
    const float* __restrict__ eattr,
    int usePerm,
    const float* __restrict__ xl, const float* __restrict__ xr,
    const float* __restrict__ We,   // [16, C]
    const float* __restrict__ att,  // [C]
    const float* __restrict__ bias, float* __restrict__ hout, int N) {
  constexpr int VPL = C / 64;
  const int lane = threadIdx.x & 63;
  // wave-uniform d so rowptr/srcp/eattr accesses become scalar loads
  int d = __builtin_amdgcn_readfirstlane(blockIdx.x * (blockDim.x >> 6) + (threadIdx.x >> 6));
  if (d >= N) return;

  float wreg[16][VPL];
  float areg[VPL];
#pragma unroll
  for (int k = 0; k < 16; ++k)
#pragma unroll
    for (int j = 0; j < VPL; ++j) wreg[k][j] = We[k * C + lane * VPL + j];
#pragma unroll
  for (int j = 0; j < VPL; ++j) areg[j] = att[lane * VPL + j];

  int beg = rowptr[d], end = rowptr[d + 1];
  float rv[VPL];
  loadv<VPL>(xr + (size_t)d * C + lane * VPL, rv);

  float m = -INFINITY, s = 0.f;
  float acc[VPL];
#pragma unroll
  for (int j = 0; j < VPL; ++j) acc[j] = 0.f;
  float sea[16];
#pragma unroll
  for (int k = 0; k < 16; ++k) sea[k] = 0.f;

  if (usePerm) {
    for (int j = beg; j < end; ++j) {
      int e = perm[j];
      int sn = src[e];
      const float* ap = eattr + (size_t)e * 16;
      float ea[16];
#pragma unroll
      for (int k = 0; k < 16; ++k) { ea[k] = ap[k]; sea[k] += ea[k]; }
      edge_update<VPL, C>(xl, sn, lane, rv, wreg, areg, ea, m, s, acc);
    }
  } else {
    for (int j = beg; j < end; ++j) {
      int sn = srcp[j];
      const float* ap = eap + (size_t)j * 16;
      float ea[16];
#pragma unroll
      for (int k = 0; k < 16; ++k) { ea[k] = ap[k]; sea[k] += ea[k]; }
      edge_update<VPL, C>(xl, sn, lane, rv, wreg, areg, ea, m, s, acc);
    }
  }
  // self loop with mean edge_attr (fill_value='mean'), processed as the last edge
  {
    int cdeg = end - beg;
    if (cdeg < 1) cdeg = 1;
    float invc = 1.f / (float)cdeg;
    float ea[16];
#pragma unroll
    for (int k = 0; k < 16; ++k) ea[k] = sea[k] * invc;
    edge_update<VPL, C>(xl, d, lane, rv, wreg, areg, ea, m, s, acc);
  }

  float inv = 1.f / (s + 1e-16f);
  if constexpr (!FINAL) {
    float res[VPL];
#pragma unroll
    for (int j = 0; j < VPL; ++j) {
      float v = acc[j] * inv + bias[lane * VPL + j];
      res[j] = v > 0.f ? v : 0.f;
    }
    storev<VPL>(hout + (size_t)d * C + lane * VPL, res);
  } else {
    float v[VPL];
#pragma unroll
    for (int j = 0; j < VPL; ++j) v[j] = acc[j] * inv;
#pragma unroll
    for (int j = 0; j < VPL; ++j) {
      v[j] += __shfl_xor(v[j], 16);
      v[j] += __shfl_xor(v[j], 32);
    }
    if (lane < 16) {
      float res[VPL];
#pragma unroll
      for (int j = 0; j < VPL; ++j) {
        float val = 0.25f * v[j] + bias[lane * VPL + j];
        res[j] = val > 0.f ? val : 0.f;
      }
      storev<VPL>(hout + (size_t)d * 64 + lane * VPL, res);
    }
  }
}

// ---------------- global mean pool: segmented reduction (batch is SORTED) ----------------
__global__ __launch_bounds__(256) void pool_kernel(
    const float* __restrict__ h3, const int* __restrict__ batch,
    float* __restrict__ gsum, float* __restrict__ gcnt, int N) {
  const int lane = threadIdx.x & 63;
  const int w = blockIdx.x * (blockDim.x >> 6) + (threadIdx.x >> 6);
  const int nw = gridDim.x * (blockDim.x >> 6);
  const int chunk = (N + nw - 1) / nw;
  int i0 = w * chunk;
  int i1 = i0 + chunk; if (i1 > N) i1 = N;
  if (i0 >= i1) return;
  int cur = batch[i0];
  float acc = 0.f;
  int cnt = 0;
  for (int i = i0; i < i1; ++i) {
    int g = batch[i];
    if (g != cur) {
      atomicAdd(&gsum[(size_t)cur * 64 + lane], acc);
      if (lane == 0) atomicAdd(&gcnt[cur], (float)cnt);
      acc = 0.f; cnt = 0; cur = g;
    }
    acc += h3[(size_t)i * 64 + lane];
    ++cnt;
  }
  atomicAdd(&gsum[(size_t)cur * 64 + lane], acc);
  if (lane == 0) atomicAdd(&gcnt[cur], (float)cnt);
}

__global__ void final_kernel(const float* __restrict__ gsum, const float* __restrict__ gcnt,
                             const float* __restrict__ Wlin, const float* __restrict__ blin,
                             float* __restrict__ out) {
  int idx = blockIdx.x * blockDim.x + threadIdx.x;
  if (idx >= GG * 16) return;
  int g = idx >> 4, o = idx & 15;
  float c = gcnt[g];
  c = c > 1.f ? c : 1.f;
  float inv = 1.f / c;
  float acc = blin[o];
  for (int f = 0; f < 64; ++f) acc = fmaf(gsum[(size_t)g * 64 + f] * inv, Wlin[f * 16 + o], acc);
  out[idx] = acc;
}

// ---------------- launch ----------------
extern "C" void kernel_launch(void* const* d_in, const int* in_sizes, int n_in,
                              void* d_out, int out_size, void* d_ws, size_t ws_size,
                              hipStream_t stream) {
  (void)in_sizes; (void)n_in; (void)out_size;
  const float* x     = (const float*)d_in[0];
  const int*   eidx  = (const int*)d_in[1];
  const int*   batch = (const int*)d_in[2];
  const float* eattr = (const float*)d_in[3];
  const float* Wl0 = (const float*)d_in[4];  const float* bl0 = (const float*)d_in[5];
  const float* Wr0 = (const float*)d_in[6];  const float* br0 = (const float*)d_in[7];
  const float* We0 = (const float*)d_in[8];  const float* att0 = (const float*)d_in[9];
  const float* bo0 = (const float*)d_in[10];
  const float* Wlh = (const float*)d_in[11]; const float* blh = (const float*)d_in[12];
  const float* Wrh = (const float*)d_in[13]; const float* brh = (const float*)d_in[14];
  const float* Weh = (const float*)d_in[15]; const float* atth = (const float*)d_in[16];
  const float* boh = (const float*)d_in[17];
  const float* Wlf = (const float*)d_in[18]; const float* blf = (const float*)d_in[19];
  const float* Wrf = (const float*)d_in[20]; const float* brf = (const float*)d_in[21];
  const float* Wef = (const float*)d_in[22]; const float* attf = (const float*)d_in[23];
  const float* bof = (const float*)d_in[24];
  const float* Wlin = (const float*)d_in[25]; const float* blin = (const float*)d_in[26];

  const int* src = eidx;
  const int* dst = eidx + EE;

  char* ws = (char*)d_ws;
  size_t off = 0;
  auto take = [&](size_t bytes) -> void* {
    void* p = ws + off;
    off += (bytes + 1023) & ~(size_t)1023;
    return p;
  };
  float* xl     = (float*)take((size_t)NN * 256 * 4);
  float* xr     = (float*)take((size_t)NN * 256 * 4);
  float* hbuf   = (float*)take((size_t)NN * 128 * 4);
  int* hist     = (int*)take((size_t)NN * 4);
  int* rowptr   = (int*)take((size_t)(NN + 1) * 4);
  int* cursor   = (int*)take((size_t)NN * 4);
  int* perm     = (int*)take((size_t)EE * 4);
  int* bsum     = (int*)take(256);
  int* boff     = (int*)take(256);
  float* gsum   = (float*)take((size_t)GG * 64 * 4);
  float* gcnt   = (float*)take((size_t)GG * 4);
  // optional permuted-edge buffers (sequential reads in the hot loop)
  size_t perm_need = off + (((size_t)EE * 4 + 1023) & ~(size_t)1023)
                   + (((size_t)EE * 16 * 4 + 1023) & ~(size_t)1023);
  int usePerm = (ws_size >= perm_need) ? 0 : 1;  // 0 => permuted srcp/eap path
  int* srcp = nullptr; float* eap = nullptr;
  if (!usePerm) {
    srcp = (int*)take((size_t)EE * 4);
    eap  = (float*)take((size_t)EE * 16 * 4);
  }

  // ---- CSR by dst (dst fixed across layers; rebuilt every call) ----
  hipMemsetAsync(hist, 0, (size_t)NN * 4, stream);
  hipMemsetAsync(gsum, 0, (size_t)GG * 64 * 4, stream);
  hipMemsetAsync(gcnt, 0, (size_t)GG * 4, stream);
  hist_kernel<<<(EE + 255) / 256, 256, 0, stream>>>(dst, hist, EE);
  int nsb = (NN + SCAN_B - 1) / SCAN_B;
  scan_block_kernel<<<nsb, SCAN_B, 0, stream>>>(hist, rowptr + 1, bsum, NN);
  scan_totals_kernel<<<1, 64, 0, stream>>>(bsum, boff, nsb);
  add_offsets_kernel<<<nsb, SCAN_B, 0, stream>>>(rowptr, boff, NN);
  copy_cursor_kernel<<<(NN + 255) / 256, 256, 0, stream>>>(rowptr, cursor, NN);
  scatter_perm_kernel<<<(EE + 255) / 256, 256, 0, stream>>>(dst, cursor, perm, EE);
  if (!usePerm)
    permute_kernel<<<(EE + 255) / 256, 256, 0, stream>>>(perm, src, eattr, srcp, eap, EE);

  const int AGG_BLOCKS = (NN + 3) / 4;

  // ---- Layer 1 (C=128) ----
  dim3 g12((NN + 127) / 128, 2);
  gemm_dual_kernel<<<g12, 256, 0, stream>>>(x, Wl0, bl0, xl, Wr0, br0, xr, NN, 128);
  gat_fused_kernel<128, false><<<AGG_BLOCKS, 256, 0, stream>>>(
      rowptr, srcp, eap, perm, src, eattr, usePerm, xl, xr, We0, att0, bo0, hbuf, NN);
  // ---- Layer 2 (C=128) ----
  gemm_dual_kernel<<<g12, 256, 0, stream>>>(hbuf, Wlh, blh, xl, Wrh, brh, xr, NN, 128);
  gat_fused_kernel<128, false><<<AGG_BLOCKS, 256, 0, stream>>>(
      rowptr, srcp, eap, perm, src, eattr, usePerm, xl, xr, Weh, atth, boh, hbuf, NN);
  // ---- Layer 3 (C=256, mean over heads) ----
  dim3 g3((NN + 127) / 128, 4);
  gemm_dual_kernel<<<g3, 256, 0, stream>>>(hbuf, Wlf, blf, xl, Wrf, brf, xr, NN, 256);
  gat_fused_kernel<256, true><<<AGG_BLOCKS, 256, 0, stream>>>(
      rowptr, srcp, eap, perm, src, eattr, usePerm, xl, xr, Wef, attf, bof, hbuf, NN);
  // ---- pool + final linear ----
  pool_kernel<<<128, 256, 0, stream>>>(hbuf, batch, gsum, gcnt, NN);
  final_kernel<<<4, 256, 0, stream>>>(gsum, gcnt, Wlin, blin, (float*)d_out);
}

// Round 4
// 887.501 us; speedup vs baseline: 2.2939x; 1.1703x over previous
//
#include <hip/hip_runtime.h>
#include <cstddef>

#define NSLOPE 0.2f

constexpr int NN = 50000;
constexpr int EE = 800000;
constexpr int GG = 64;
constexpr int SCAN_B = 1024;

// ---------------- CSR build (dst-sorted edge permutation) ----------------
__global__ void hist_kernel(const int* __restrict__ dst, int* __restrict__ hist, int E) {
  int e = blockIdx.x * blockDim.x + threadIdx.x;
  if (e < E) atomicAdd(&hist[dst[e]], 1);
}

__global__ void scan_block_kernel(const int* __restrict__ in, int* __restrict__ out,
                                  int* __restrict__ bsum, int n) {
  __shared__ int tmp[SCAN_B];
  int gid = blockIdx.x * SCAN_B + threadIdx.x;
  int v = (gid < n) ? in[gid] : 0;
  tmp[threadIdx.x] = v;
  __syncthreads();
  for (int off = 1; off < SCAN_B; off <<= 1) {
    int t = (threadIdx.x >= off) ? tmp[threadIdx.x - off] : 0;
    __syncthreads();
    tmp[threadIdx.x] += t;
    __syncthreads();
  }
  if (gid < n) out[gid] = tmp[threadIdx.x];
  if (threadIdx.x == SCAN_B - 1) bsum[blockIdx.x] = tmp[threadIdx.x];
}

__global__ void scan_totals_kernel(const int* __restrict__ bsum, int* __restrict__ boff, int nb) {
  if (blockIdx.x == 0 && threadIdx.x == 0) {
    int run = 0;
    for (int i = 0; i < nb; ++i) { boff[i] = run; run += bsum[i]; }
  }
}

__global__ void add_offsets_kernel(int* __restrict__ rowptr, const int* __restrict__ boff, int n) {
  int gid = blockIdx.x * SCAN_B + threadIdx.x;
  if (gid == 0) rowptr[0] = 0;
  if (gid < n) rowptr[1 + gid] += boff[blockIdx.x];
}

__global__ void copy_cursor_kernel(const int* __restrict__ rowptr, int* __restrict__ cursor, int n) {
  int i = blockIdx.x * blockDim.x + threadIdx.x;
  if (i < n) cursor[i] = rowptr[i];
}

__global__ void scatter_perm_kernel(const int* __restrict__ dst, int* __restrict__ cursor,
                                    int* __restrict__ perm, int E) {
  int e = blockIdx.x * blockDim.x + threadIdx.x;
  if (e < E) {
    int pos = atomicAdd(&cursor[dst[e]], 1);
    perm[pos] = e;
  }
}

// permute src + eattr into dst-sorted order so the hot loop reads sequentially
__global__ void permute_kernel(const int* __restrict__ perm, const int* __restrict__ src,
                               const float* __restrict__ eattr,
                               int* __restrict__ srcp, float* __restrict__ eap, int E) {
  int j = blockIdx.x * blockDim.x + threadIdx.x;
  if (j >= E) return;
  int e = perm[j];
  srcp[j] = src[e];
  const float4* a = reinterpret_cast<const float4*>(eattr + (size_t)e * 16);
  float4* b = reinterpret_cast<float4*>(eap + (size_t)j * 16);
  b[0] = a[0]; b[1] = a[1]; b[2] = a[2]; b[3] = a[3];
}

// per-dst mean edge_attr (self-loop fill_value='mean'), computed once per call
__global__ void mean_attr_kernel(const int* __restrict__ rowptr, const float* __restrict__ eap,
                                 const int* __restrict__ perm, const float* __restrict__ eattr,
                                 int usePerm, float* __restrict__ meanattr, int N) {
  int idx = blockIdx.x * blockDim.x + threadIdx.x;
  if (idx >= N * 16) return;
  int i = idx >> 4, k = idx & 15;
  int beg = rowptr[i], end = rowptr[i + 1];
  float acc = 0.f;
  if (usePerm) {
    for (int j = beg; j < end; ++j) acc += eattr[(size_t)perm[j] * 16 + k];
  } else {
    for (int j = beg; j < end; ++j) acc += eap[(size_t)j * 16 + k];
  }
  int c = end - beg; if (c < 1) c = 1;
  meanattr[idx] = acc / (float)c;
}

// ---------------- fused dual GEMM: Y0 = X@W0+b0, Y1 = X@W1+b1 (K=128) ----------------
__global__ __launch_bounds__(256) void gemm_dual_kernel(
    const float* __restrict__ X,
    const float* __restrict__ W0, const float* __restrict__ b0, float* __restrict__ Y0,
    const float* __restrict__ W1, const float* __restrict__ b1, float* __restrict__ Y1,
    int M, int Nc) {
  constexpr int K = 128, BM = 128, BN = 128, BK = 16;
  __shared__ float As[BK][BM + 4];
  __shared__ float Bs[BK][BN];
  int nb = Nc >> 7;
  int half = blockIdx.y / nb;
  int cb = blockIdx.y % nb;
  const float* W = half ? W1 : W0;
  const float* bias = half ? b1 : b0;
  float* Y = half ? Y1 : Y0;
  int row0 = blockIdx.x * BM;
  int col0 = cb * BN;
  int tid = threadIdx.x;
  int tr = tid >> 4, tc = tid & 15;
  float acc[8][8];
#pragma unroll
  for (int i = 0; i < 8; ++i)
#pragma unroll
    for (int j = 0; j < 8; ++j) acc[i][j] = 0.f;

  for (int k0 = 0; k0 < K; k0 += BK) {
#pragma unroll
    for (int u = 0; u < 2; ++u) {
      int idx = tid + u * 256;
      int r = idx >> 2, c4 = (idx & 3) << 2;
      int row = row0 + r;
      float4 v = make_float4(0.f, 0.f, 0.f, 0.f);
      if (row < M) v = *reinterpret_cast<const float4*>(X + (size_t)row * K + k0 + c4);
      As[c4 + 0][r] = v.x; As[c4 + 1][r] = v.y; As[c4 + 2][r] = v.z; As[c4 + 3][r] = v.w;
    }
#pragma unroll
    for (int u = 0; u < 2; ++u) {
      int idx = tid + u * 256;
      int r = idx >> 5, c4 = (idx & 31) << 2;
      *reinterpret_cast<float4*>(&Bs[r][c4]) =
          *reinterpret_cast<const float4*>(W + (size_t)(k0 + r) * Nc + col0 + c4);
    }
    __syncthreads();
#pragma unroll
    for (int kk = 0; kk < BK; ++kk) {
      float a[8], b[8];
      *reinterpret_cast<float4*>(&a[0]) = *reinterpret_cast<const float4*>(&As[kk][tr * 8]);
      *reinterpret_cast<float4*>(&a[4]) = *reinterpret_cast<const float4*>(&As[kk][tr * 8 + 4]);
      *reinterpret_cast<float4*>(&b[0]) = *reinterpret_cast<const float4*>(&Bs[kk][tc * 8]);
      *reinterpret_cast<float4*>(&b[4]) = *reinterpret_cast<const float4*>(&Bs[kk][tc * 8 + 4]);
#pragma unroll
      for (int i = 0; i < 8; ++i)
#pragma unroll
        for (int j = 0; j < 8; ++j) acc[i][j] = fmaf(a[i], b[j], acc[i][j]);
    }
    __syncthreads();
  }
#pragma unroll
  for (int i = 0; i < 8; ++i) {
    int row = row0 + tr * 8 + i;
    if (row >= M) continue;
    float* yp = Y + (size_t)row * Nc + col0 + tc * 8;
    const float* bp = bias + col0 + tc * 8;
    float4 o0 = make_float4(acc[i][0] + bp[0], acc[i][1] + bp[1], acc[i][2] + bp[2], acc[i][3] + bp[3]);
    float4 o1 = make_float4(acc[i][4] + bp[4], acc[i][5] + bp[5], acc[i][6] + bp[6], acc[i][7] + bp[7]);
    *reinterpret_cast<float4*>(yp) = o0;
    *reinterpret_cast<float4*>(yp + 4) = o1;
  }
}

// ---------------- vector load/store helpers ----------------
template <int VPL>
__device__ __forceinline__ void loadv(const float* p, float* v) {
  if constexpr (VPL == 2) {
    float2 t = *reinterpret_cast<const float2*>(p);
    v[0] = t.x; v[1] = t.y;
  } else {
    float4 t = *reinterpret_cast<const float4*>(p);
    v[0] = t.x; v[1] = t.y; v[2] = t.z; v[3] = t.w;
  }
}
template <int VPL>
__device__ __forceinline__ void storev(float* p, const float* v) {
  if constexpr (VPL == 2) {
    *reinterpret_cast<float2*>(p) = make_float2(v[0], v[1]);
  } else {
    *reinterpret_cast<float4*>(p) = make_float4(v[0], v[1], v[2], v[3]);
  }
}

// per-edge logit: leaky-relu(xl+xr+ea@We) . att, reduced across the 16 lanes of each head
template <int VPL>
__device__ __forceinline__ float lrelu_dot(const float* xv, const float* rv,
                                           const float (*wreg)[VPL], const float* areg,
                                           const float* ea) {
  float part = 0.f;
#pragma unroll
  for (int j = 0; j < VPL; ++j) {
    float z = xv[j] + rv[j];
#pragma unroll
    for (int k = 0; k < 16; ++k) z = fmaf(ea[k], wreg[k][j], z);
    z = (z > 0.f) ? z : NSLOPE * z;
    part = fmaf(z, areg[j], part);
  }
  part += __shfl_xor(part, 1);
  part += __shfl_xor(part, 2);
  part += __shfl_xor(part, 4);
  part += __shfl_xor(part, 8);
  return part;
}

// batched online-softmax update over EB edges: EB independent gathers + logit
// chains (ILP hides load/shfl/exp latency), ONE rescale of (m,s,acc) per group.
template <int EB, int VPL, int C>
__device__ __forceinline__ void process_group(
    const int* __restrict__ srcp, const float* __restrict__ eap, int j,
    const float* __restrict__ xl, int lane, const float* rv,
    const float (*wreg)[VPL], const float* areg,
    float& m, float& s, float* acc) {
  int sn[EB];
#pragma unroll
  for (int u = 0; u < EB; ++u) sn[u] = srcp[j + u];
  float xv[EB][VPL];
#pragma unroll
  for (int u = 0; u < EB; ++u) loadv<VPL>(xl + (size_t)sn[u] * C + lane * VPL, xv[u]);
  float lg[EB];
#pragma unroll
  for (int u = 0; u < EB; ++u) {
    const float* ap = eap + (size_t)(j + u) * 16;
    float ea[16];
#pragma unroll
    for (int k = 0; k < 16; ++k) ea[k] = ap[k];
    lg[u] = lrelu_dot<VPL>(xv[u], rv, wreg, areg, ea);
  }
  float newm = m;
#pragma unroll
  for (int u = 0; u < EB; ++u) newm = fmaxf(newm, lg[u]);
  float sc = __expf(m - newm);  // 0 when m == -inf
  float p[EB], ps = 0.f;
#pragma unroll
  for (int u = 0; u < EB; ++u) { p[u] = __expf(lg[u] - newm); ps += p[u]; }
  s = fmaf(s, sc, ps);
#pragma unroll
  for (int jj = 0; jj < VPL; ++jj) {
    float t = p[0] * xv[0][jj];
#pragma unroll
    for (int u = 1; u < EB; ++u) t = fmaf(p[u], xv[u][jj], t);
    acc[jj] = fmaf(acc[jj], sc, t);
  }
  m = newm;
}

// single edge with explicit src index + ea array (self-loop / fallback path)
template <int VPL, int C>
__device__ __forceinline__ void process_one(
    int sn, const float* ea,
    const float* __restrict__ xl, int lane, const float* rv,
    const float (*wreg)[VPL], const float* areg,
    float& m, float& s, float* acc) {
  float xv[VPL];
  loadv<VPL>(xl + (size_t)sn * C + lane * VPL, xv);
  float lg = lrelu_dot<VPL>(xv, rv, wreg, areg, ea);
  float newm = fmaxf(m, lg);
  float sc = __expf(m - newm);
  float p = __expf(lg - newm);
  s = fmaf(s, sc, p);
#pragma unroll
  for (int jj = 0; jj < VPL; ++jj) acc[jj] = fmaf(acc[jj], sc, p * xv[jj]);
  m = newm;
}

// ---------------- fused GATv2 edge+softmax+aggregate: one wave per dst ----------------
template <int C, bool FINAL>
__global__ __launch_bounds__(256) void gat_fused_kernel(
    const int* __restrict__ rowptr,
    const int* __restrict__ srcp, const float* __restrict__ eap,  // permuted (optional)
    const int* __restrict__ perm, const int* __restrict__ src,
    const float* __restrict__ eattr, const float* __restrict__ meanattr,
    int usePerm,
    const float* __restrict__ xl, const float* __restrict__ xr,
    const float* __restrict__ We,   // [16, C]
    const float* __restrict__ att,  // [C]
    const float* __restrict__ bias, float* __restrict__ hout, int N) {
  constexpr int VPL = C / 64;
  constexpr int EB = (C == 128) ? 4 : 2;  // edge batch; smaller at C=256 for VGPRs
  const int lane = threadIdx.x & 63;
  // wave-uniform d so rowptr/srcp/eap accesses become scalar loads
  int d = __builtin_amdgcn_readfirstlane(blockIdx.x * (blockDim.x >> 6) + (threadIdx.x >> 6));
  if (d >= N) return;

  float wreg[16][VPL];
  float areg[VPL];
#pragma unroll
  for (int k = 0; k < 16; ++k)
#pragma unroll
    for (int j = 0; j < VPL; ++j) wreg[k][j] = We[k * C + lane * VPL + j];
#pragma unroll
  for (int j = 0; j < VPL; ++j) areg[j] = att[lane * VPL + j];

  int beg = rowptr[d], end = rowptr[d + 1];
  float rv[VPL];
  loadv<VPL>(xr + (size_t)d * C + lane * VPL, rv);

  float m = -INFINITY, s = 0.f;
  float acc[VPL];
#pragma unroll
  for (int j = 0; j < VPL; ++j) acc[j] = 0.f;

  if (!usePerm) {
    int j = beg;
    for (; j + EB <= end; j += EB)
      process_group<EB, VPL, C>(srcp, eap, j, xl, lane, rv, wreg, areg, m, s, acc);
    for (; j < end; ++j)
      process_group<1, VPL, C>(srcp, eap, j, xl, lane, rv, wreg, areg, m, s, acc);
  } else {
    for (int j = beg; j < end; ++j) {
      int e = perm[j];
      int sn = src[e];
      const float* ap = eattr + (size_t)e * 16;
      float ea[16];
#pragma unroll
      for (int k = 0; k < 16; ++k) ea[k] = ap[k];
      process_one<VPL, C>(sn, ea, xl, lane, rv, wreg, areg, m, s, acc);
    }
  }
  // self loop with mean edge_attr (fill_value='mean'), processed as the last edge
  {
    const float* mp = meanattr + (size_t)d * 16;
    float ea[16];
#pragma unroll
    for (int k = 0; k < 16; ++k) ea[k] = mp[k];
    process_one<VPL, C>(d, ea, xl, lane, rv, wreg, areg, m, s, acc);
  }

  float inv = 1.f / (s + 1e-16f);
  if constexpr (!FINAL) {
    float res[VPL];
#pragma unroll
    for (int j = 0; j < VPL; ++j) {
      float v = acc[j] * inv + bias[lane * VPL + j];
      res[j] = v > 0.f ? v : 0.f;
    }
    storev<VPL>(hout + (size_t)d * C + lane * VPL, res);
  } else {
    float v[VPL];
#pragma unroll
    for (int j = 0; j < VPL; ++j) v[j] = acc[j] * inv;
#pragma unroll
    for (int j = 0; j < VPL; ++j) {
      v[j] += __shfl_xor(v[j], 16);
      v[j] += __shfl_xor(v[j], 32);
    }
    if (lane < 16) {
      float res[VPL];
#pragma unroll
      for (int j = 0; j < VPL; ++j) {
        float val = 0.25f * v[j] + bias[lane * VPL + j];
        res[j] = val > 0.f ? val : 0.f;
      }
      storev<VPL>(hout + (size_t)d * 64 + lane * VPL, res);
    }
  }
}

// ---------------- global mean pool: segmented reduction (batch is SORTED) ----------------
__global__ __launch_bounds__(256) void pool_kernel(
    const float* __restrict__ h3, const int* __restrict__ batch,
    float* __restrict__ gsum, float* __restrict__ gcnt, int N) {
  const int lane = threadIdx.x & 63;
  const int w = blockIdx.x * (blockDim.x >> 6) + (threadIdx.x >> 6);
  const int nw = gridDim.x * (blockDim.x >> 6);
  const int chunk = (N + nw - 1) / nw;
  int i0 = w * chunk;
  int i1 = i0 + chunk; if (i1 > N) i1 = N;
  if (i0 >= i1) return;
  int cur = batch[i0];
  float acc = 0.f;
  int cnt = 0;
  for (int i = i0; i < i1; ++i) {
    int g = batch[i];
    if (g != cur) {
      atomicAdd(&gsum[(size_t)cur * 64 + lane], acc);
      if (lane == 0) atomicAdd(&gcnt[cur], (float)cnt);
      acc = 0.f; cnt = 0; cur = g;
    }
    acc += h3[(size_t)i * 64 + lane];
    ++cnt;
  }
  atomicAdd(&gsum[(size_t)cur * 64 + lane], acc);
  if (lane == 0) atomicAdd(&gcnt[cur], (float)cnt);
}

__global__ void final_kernel(const float* __restrict__ gsum, const float* __restrict__ gcnt,
                             const float* __restrict__ Wlin, const float* __restrict__ blin,
                             float* __restrict__ out) {
  int idx = blockIdx.x * blockDim.x + threadIdx.x;
  if (idx >= GG * 16) return;
  int g = idx >> 4, o = idx & 15;
  float c = gcnt[g];
  c = c > 1.f ? c : 1.f;
  float inv = 1.f / c;
  float acc = blin[o];
  for (int f = 0; f < 64; ++f) acc = fmaf(gsum[(size_t)g * 64 + f] * inv, Wlin[f * 16 + o], acc);
  out[idx] = acc;
}

// ---------------- launch ----------------
extern "C" void kernel_launch(void* const* d_in, const int* in_sizes, int n_in,
                              void* d_out, int out_size, void* d_ws, size_t ws_size,
                              hipStream_t stream) {
  (void)in_sizes; (void)n_in; (void)out_size;
  const float* x     = (const float*)d_in[0];
  const int*   eidx  = (const int*)d_in[1];
  const int*   batch = (const int*)d_in[2];
  const float* eattr = (const float*)d_in[3];
  const float* Wl0 = (const float*)d_in[4];  const float* bl0 = (const float*)d_in[5];
  const float* Wr0 = (const float*)d_in[6];  const float* br0 = (const float*)d_in[7];
  const float* We0 = (const float*)d_in[8];  const float* att0 = (const float*)d_in[9];
  const float* bo0 = (const float*)d_in[10];
  const float* Wlh = (const float*)d_in[11]; const float* blh = (const float*)d_in[12];
  const float* Wrh = (const float*)d_in[13]; const float* brh = (const float*)d_in[14];
  const float* Weh = (const float*)d_in[15]; const float* atth = (const float*)d_in[16];
  const float* boh = (const float*)d_in[17];
  const float* Wlf = (const float*)d_in[18]; const float* blf = (const float*)d_in[19];
  const float* Wrf = (const float*)d_in[20]; const float* brf = (const float*)d_in[21];
  const float* Wef = (const float*)d_in[22]; const float* attf = (const float*)d_in[23];
  const float* bof = (const float*)d_in[24];
  const float* Wlin = (const float*)d_in[25]; const float* blin = (const float*)d_in[26];

  const int* src = eidx;
  const int* dst = eidx + EE;

  char* ws = (char*)d_ws;
  size_t off = 0;
  auto take = [&](size_t bytes) -> void* {
    void* p = ws + off;
    off += (bytes + 1023) & ~(size_t)1023;
    return p;
  };
  float* xl       = (float*)take((size_t)NN * 256 * 4);
  float* xr       = (float*)take((size_t)NN * 256 * 4);
  float* hbuf     = (float*)take((size_t)NN * 128 * 4);
  float* meanattr = (float*)take((size_t)NN * 16 * 4);
  int* hist       = (int*)take((size_t)NN * 4);
  int* rowptr     = (int*)take((size_t)(NN + 1) * 4);
  int* cursor     = (int*)take((size_t)NN * 4);
  int* perm       = (int*)take((size_t)EE * 4);
  int* bsum       = (int*)take(256);
  int* boff       = (int*)take(256);
  float* gsum     = (float*)take((size_t)GG * 64 * 4);
  float* gcnt     = (float*)take((size_t)GG * 4);
  // optional permuted-edge buffers (sequential reads in the hot loop)
  size_t perm_need = off + (((size_t)EE * 4 + 1023) & ~(size_t)1023)
                   + (((size_t)EE * 16 * 4 + 1023) & ~(size_t)1023);
  int usePerm = (ws_size >= perm_need) ? 0 : 1;  // 0 => permuted srcp/eap path
  int* srcp = nullptr; float* eap = nullptr;
  if (!usePerm) {
    srcp = (int*)take((size_t)EE * 4);
    eap  = (float*)take((size_t)EE * 16 * 4);
  }

  // ---- CSR by dst (dst fixed across layers; rebuilt every call) ----
  hipMemsetAsync(hist, 0, (size_t)NN * 4, stream);
  hipMemsetAsync(gsum, 0, (size_t)GG * 64 * 4, stream);
  hipMemsetAsync(gcnt, 0, (size_t)GG * 4, stream);
  hist_kernel<<<(EE + 255) / 256, 256, 0, stream>>>(dst, hist, EE);
  int nsb = (NN + SCAN_B - 1) / SCAN_B;
  scan_block_kernel<<<nsb, SCAN_B, 0, stream>>>(hist, rowptr + 1, bsum, NN);
  scan_totals_kernel<<<1, 64, 0, stream>>>(bsum, boff, nsb);
  add_offsets_kernel<<<nsb, SCAN_B, 0, stream>>>(rowptr, boff, NN);
  copy_cursor_kernel<<<(NN + 255) / 256, 256, 0, stream>>>(rowptr, cursor, NN);
  scatter_perm_kernel<<<(EE + 255) / 256, 256, 0, stream>>>(dst, cursor, perm, EE);
  if (!usePerm)
    permute_kernel<<<(EE + 255) / 256, 256, 0, stream>>>(perm, src, eattr, srcp, eap, EE);
  mean_attr_kernel<<<(NN * 16 + 255) / 256, 256, 0, stream>>>(rowptr, eap, perm, eattr,
                                                              usePerm, meanattr, NN);

  const int AGG_BLOCKS = (NN + 3) / 4;

  // ---- Layer 1 (C=128) ----
  dim3 g12((NN + 127) / 128, 2);
  gemm_dual_kernel<<<g12, 256, 0, stream>>>(x, Wl0, bl0, xl, Wr0, br0, xr, NN, 128);
  gat_fused_kernel<128, false><<<AGG_BLOCKS, 256, 0, stream>>>(
      rowptr, srcp, eap, perm, src, eattr, meanattr, usePerm, xl, xr, We0, att0, bo0, hbuf, NN);
  // ---- Layer 2 (C=128) ----
  gemm_dual_kernel<<<g12, 256, 0, stream>>>(hbuf, Wlh, blh, xl, Wrh, brh, xr, NN, 128);
  gat_fused_kernel<128, false><<<AGG_BLOCKS, 256, 0, stream>>>(
      rowptr, srcp, eap, perm, src, eattr, meanattr, usePerm, xl, xr, Weh, atth, boh, hbuf, NN);
  // ---- Layer 3 (C=256, mean over heads) ----
  dim3 g3((NN + 127) / 128, 4);
  gemm_dual_kernel<<<g3, 256, 0, stream>>>(hbuf, Wlf, blf, xl, Wrf, brf, xr, NN, 256);
  gat_fused_kernel<256, true><<<AGG_BLOCKS, 256, 0, stream>>>(
      rowptr, srcp, eap, perm, src, eattr, meanattr, usePerm, xl, xr, Wef, attf, bof, hbuf, NN);
  // ---- pool + final linear ----
  pool_kernel<<<128, 256, 0, stream>>>(hbuf, batch, gsum, gcnt, NN);
  final_kernel<<<4, 256, 0, stream>>>(gsum, gcnt, Wlin, blin, (float*)d_out);
}

// Round 5
// 776.383 us; speedup vs baseline: 2.6222x; 1.1431x over previous
//
#include <hip/hip_runtime.h>
#include <cstddef>

#define NSLOPE 0.2f

constexpr int NN = 50000;
constexpr int EE = 800000;
constexpr int GG = 64;
constexpr int SCAN_B = 1024;

typedef unsigned short ushort_t;
typedef __bf16 bhalf;
typedef bhalf bhalf8 __attribute__((ext_vector_type(8)));
typedef float floatx4 __attribute__((ext_vector_type(4)));

__device__ __forceinline__ ushort_t f2b(float f) {  // fp32 -> bf16 RNE
  unsigned int u = __float_as_uint(f);
  unsigned int r = (u + 0x7fffu + ((u >> 16) & 1u)) >> 16;
  return (ushort_t)r;
}
__device__ __forceinline__ float b2f(ushort_t b) {
  return __uint_as_float(((unsigned int)b) << 16);
}

// ---------------- CSR build (dst-sorted edge permutation) ----------------
__global__ void hist_kernel(const int* __restrict__ dst, int* __restrict__ hist, int E) {
  int e = blockIdx.x * blockDim.x + threadIdx.x;
  if (e < E) atomicAdd(&hist[dst[e]], 1);
}

__global__ void scan_block_kernel(const int* __restrict__ in, int* __restrict__ out,
                                  int* __restrict__ bsum, int n) {
  __shared__ int tmp[SCAN_B];
  int gid = blockIdx.x * SCAN_B + threadIdx.x;
  int v = (gid < n) ? in[gid] : 0;
  tmp[threadIdx.x] = v;
  __syncthreads();
  for (int off = 1; off < SCAN_B; off <<= 1) {
    int t = (threadIdx.x >= off) ? tmp[threadIdx.x - off] : 0;
    __syncthreads();
    tmp[threadIdx.x] += t;
    __syncthreads();
  }
  if (gid < n) out[gid] = tmp[threadIdx.x];
  if (threadIdx.x == SCAN_B - 1) bsum[blockIdx.x] = tmp[threadIdx.x];
}

__global__ void scan_totals_kernel(const int* __restrict__ bsum, int* __restrict__ boff, int nb) {
  if (blockIdx.x == 0 && threadIdx.x == 0) {
    int run = 0;
    for (int i = 0; i < nb; ++i) { boff[i] = run; run += bsum[i]; }
  }
}

__global__ void add_offsets_kernel(int* __restrict__ rowptr, const int* __restrict__ boff, int n) {
  int gid = blockIdx.x * SCAN_B + threadIdx.x;
  if (gid == 0) rowptr[0] = 0;
  if (gid < n) rowptr[1 + gid] += boff[blockIdx.x];
}

__global__ void copy_cursor_kernel(const int* __restrict__ rowptr, int* __restrict__ cursor, int n) {
  int i = blockIdx.x * blockDim.x + threadIdx.x;
  if (i < n) cursor[i] = rowptr[i];
}

__global__ void scatter_perm_kernel(const int* __restrict__ dst, int* __restrict__ cursor,
                                    int* __restrict__ perm, int E) {
  int e = blockIdx.x * blockDim.x + threadIdx.x;
  if (e < E) {
    int pos = atomicAdd(&cursor[dst[e]], 1);
    perm[pos] = e;
  }
}

// permute src + eattr into dst-sorted order so the hot loop reads sequentially
__global__ void permute_kernel(const int* __restrict__ perm, const int* __restrict__ src,
                               const float* __restrict__ eattr,
                               int* __restrict__ srcp, float* __restrict__ eap, int E) {
  int j = blockIdx.x * blockDim.x + threadIdx.x;
  if (j >= E) return;
  int e = perm[j];
  srcp[j] = src[e];
  const float4* a = reinterpret_cast<const float4*>(eattr + (size_t)e * 16);
  float4* b = reinterpret_cast<float4*>(eap + (size_t)j * 16);
  b[0] = a[0]; b[1] = a[1]; b[2] = a[2]; b[3] = a[3];
}

// per-dst mean edge_attr (self-loop fill_value='mean'), computed once per call
__global__ void mean_attr_kernel(const int* __restrict__ rowptr, const float* __restrict__ eap,
                                 const int* __restrict__ perm, const float* __restrict__ eattr,
                                 int usePerm, float* __restrict__ meanattr, int N) {
  int idx = blockIdx.x * blockDim.x + threadIdx.x;
  if (idx >= N * 16) return;
  int i = idx >> 4, k = idx & 15;
  int beg = rowptr[i], end = rowptr[i + 1];
  float acc = 0.f;
  if (usePerm) {
    for (int j = beg; j < end; ++j) acc += eattr[(size_t)perm[j] * 16 + k];
  } else {
    for (int j = beg; j < end; ++j) acc += eap[(size_t)j * 16 + k];
  }
  int c = end - beg; if (c < 1) c = 1;
  meanattr[idx] = acc / (float)c;
}

// ---------------- bf16 conversion / weight transpose prep ----------------
__global__ void f2b_kernel(const float* __restrict__ in, ushort_t* __restrict__ out, int n4) {
  int i = blockIdx.x * blockDim.x + threadIdx.x;
  if (i >= n4) return;
  float4 v = reinterpret_cast<const float4*>(in)[i];
  ushort4 o = make_ushort4(f2b(v.x), f2b(v.y), f2b(v.z), f2b(v.w));
  reinterpret_cast<ushort4*>(out)[i] = o;
}

// Wt[n][k] = bf16(W[k][n]) for 6 weight matrices, K=128
__global__ void prep_w_kernel(const float* W0, ushort_t* T0, int n0,
                              const float* W1, ushort_t* T1, int n1,
                              const float* W2, ushort_t* T2, int n2,
                              const float* W3, ushort_t* T3, int n3,
                              const float* W4, ushort_t* T4, int n4,
                              const float* W5, ushort_t* T5, int n5) {
  const float* W; ushort_t* T; int Nc;
  switch (blockIdx.y) {
    case 0: W = W0; T = T0; Nc = n0; break;
    case 1: W = W1; T = T1; Nc = n1; break;
    case 2: W = W2; T = T2; Nc = n2; break;
    case 3: W = W3; T = T3; Nc = n3; break;
    case 4: W = W4; T = T4; Nc = n4; break;
    default: W = W5; T = T5; Nc = n5; break;
  }
  int idx = blockIdx.x * blockDim.x + threadIdx.x;
  if (idx >= Nc * 128) return;
  int n = idx >> 7, k = idx & 127;
  T[idx] = f2b(W[(size_t)k * Nc + n]);
}

// -------- dual bf16 MFMA GEMM (B^T layout): Y{0,1} = bf16(Xb @ W{0,1} + b{0,1}) --------
// Xb: [M x 128] bf16 row-major. Wt: [Nc x 128] bf16 (pre-transposed). K = 128 fixed.
__global__ __launch_bounds__(256) void gemm_bt_dual_bf16(
    const ushort_t* __restrict__ Xb,
    const ushort_t* __restrict__ Wt0, const float* __restrict__ b0, ushort_t* __restrict__ Y0,
    const ushort_t* __restrict__ Wt1, const float* __restrict__ b1, ushort_t* __restrict__ Y1,
    int M, int Nc) {
  constexpr int K = 128, BM = 128, BN = 128, LDT = 136;  // +8 bf16 pad = 16B, keeps b128 alignment
  __shared__ ushort_t Als[BM * LDT];
  __shared__ ushort_t Bls[BN * LDT];
  int nb = Nc >> 7;
  int half = blockIdx.y / nb;
  int cb = blockIdx.y % nb;
  const ushort_t* Wt = half ? Wt1 : Wt0;
  const float* bias = half ? b1 : b0;
  ushort_t* Y = half ? Y1 : Y0;
  int r0 = blockIdx.x * BM;
  int col0 = cb * BN;
  int tid = threadIdx.x;
  // stage full K panels: 32 threads/row (4 bf16 each), 8 rows/step, 16 steps
  {
    int rl = tid >> 5;
    int kq = (tid & 31) * 4;
#pragma unroll
    for (int s = 0; s < 16; ++s) {
      int row = rl + s * 8;
      int grow = r0 + row;
      ushort4 v = make_ushort4(0, 0, 0, 0);
      if (grow < M) v = *reinterpret_cast<const ushort4*>(Xb + (size_t)grow * K + kq);
      *reinterpret_cast<ushort4*>(&Als[row * LDT + kq]) = v;
      ushort4 wv = *reinterpret_cast<const ushort4*>(Wt + (size_t)(col0 + row) * K + kq);
      *reinterpret_cast<ushort4*>(&Bls[row * LDT + kq]) = wv;
    }
  }
  __syncthreads();
  int lane = tid & 63;
  int w = tid >> 6;
  int m0 = (w >> 1) * 64;
  int n0 = (w & 1) * 64;
  int rin = lane & 15, quad = lane >> 4;
  floatx4 acc[4][4];
#pragma unroll
  for (int i = 0; i < 4; ++i)
#pragma unroll
    for (int j = 0; j < 4; ++j) acc[i][j] = (floatx4){0.f, 0.f, 0.f, 0.f};
#pragma unroll
  for (int kt = 0; kt < 4; ++kt) {
    int ko = kt * 32 + quad * 8;
    bhalf8 af[4], bf[4];
#pragma unroll
    for (int i = 0; i < 4; ++i)
      af[i] = *reinterpret_cast<const bhalf8*>(&Als[(m0 + i * 16 + rin) * LDT + ko]);
#pragma unroll
    for (int i = 0; i < 4; ++i)
      bf[i] = *reinterpret_cast<const bhalf8*>(&Bls[(n0 + i * 16 + rin) * LDT + ko]);
#pragma unroll
    for (int mi = 0; mi < 4; ++mi)
#pragma unroll
      for (int ni = 0; ni < 4; ++ni)
        acc[mi][ni] = __builtin_amdgcn_mfma_f32_16x16x32_bf16(af[mi], bf[ni], acc[mi][ni], 0, 0, 0);
  }
#pragma unroll
  for (int ni = 0; ni < 4; ++ni) {
    int gcol = col0 + n0 + ni * 16 + rin;
    float bb = bias[gcol];
#pragma unroll
    for (int mi = 0; mi < 4; ++mi) {
      int growb = r0 + m0 + mi * 16 + quad * 4;
#pragma unroll
      for (int r = 0; r < 4; ++r) {
        int grow = growb + r;
        if (grow < M) Y[(size_t)grow * Nc + gcol] = f2b(acc[mi][ni][r] + bb);
      }
    }
  }
}

// ---------------- bf16 vector load/store helpers ----------------
template <int VPL>
__device__ __forceinline__ void loadb(const ushort_t* p, float* v) {
  if constexpr (VPL == 2) {
    ushort2 t = *reinterpret_cast<const ushort2*>(p);
    v[0] = b2f(t.x); v[1] = b2f(t.y);
  } else {
    ushort4 t = *reinterpret_cast<const ushort4*>(p);
    v[0] = b2f(t.x); v[1] = b2f(t.y); v[2] = b2f(t.z); v[3] = b2f(t.w);
  }
}
template <int VPL>
__device__ __forceinline__ void storeb(ushort_t* p, const float* v) {
  if constexpr (VPL == 2) {
    *reinterpret_cast<ushort2*>(p) = make_ushort2(f2b(v[0]), f2b(v[1]));
  } else {
    *reinterpret_cast<ushort4*>(p) = make_ushort4(f2b(v[0]), f2b(v[1]), f2b(v[2]), f2b(v[3]));
  }
}

// per-edge logit: leaky-relu(xl+xr+ea@We) . att, reduced across the 16 lanes of each head
template <int VPL>
__device__ __forceinline__ float lrelu_dot(const float* xv, const float* rv,
                                           const float (*wreg)[VPL], const float* areg,
                                           const float* ea) {
  float part = 0.f;
#pragma unroll
  for (int j = 0; j < VPL; ++j) {
    float z = xv[j] + rv[j];
#pragma unroll
    for (int k = 0; k < 16; ++k) z = fmaf(ea[k], wreg[k][j], z);
    z = (z > 0.f) ? z : NSLOPE * z;
    part = fmaf(z, areg[j], part);
  }
  part += __shfl_xor(part, 1);
  part += __shfl_xor(part, 2);
  part += __shfl_xor(part, 4);
  part += __shfl_xor(part, 8);
  return part;
}

// batched online-softmax update over EB edges: EB independent gathers + logit
// chains (ILP hides load/shfl/exp latency), ONE rescale of (m,s,acc) per group.
template <int EB, int VPL, int C>
__device__ __forceinline__ void process_group(
    const int* __restrict__ srcp, const float* __restrict__ eap, int j,
    const ushort_t* __restrict__ xl, int lane, const float* rv,
    const float (*wreg)[VPL], const float* areg,
    float& m, float& s, float* acc) {
  int sn[EB];
#pragma unroll
  for (int u = 0; u < EB; ++u) sn[u] = srcp[j + u];
  float xv[EB][VPL];
#pragma unroll
  for (int u = 0; u < EB; ++u) loadb<VPL>(xl + (size_t)sn[u] * C + lane * VPL, xv[u]);
  float lg[EB];
#pragma unroll
  for (int u = 0; u < EB; ++u) {
    const float* ap = eap + (size_t)(j + u) * 16;
    float ea[16];
#pragma unroll
    for (int k = 0; k < 16; ++k) ea[k] = ap[k];
    lg[u] = lrelu_dot<VPL>(xv[u], rv, wreg, areg, ea);
  }
  float newm = m;
#pragma unroll
  for (int u = 0; u < EB; ++u) newm = fmaxf(newm, lg[u]);
  float sc = __expf(m - newm);  // 0 when m == -inf
  float p[EB], ps = 0.f;
#pragma unroll
  for (int u = 0; u < EB; ++u) { p[u] = __expf(lg[u] - newm); ps += p[u]; }
  s = fmaf(s, sc, ps);
#pragma unroll
  for (int jj = 0; jj < VPL; ++jj) {
    float t = p[0] * xv[0][jj];
#pragma unroll
    for (int u = 1; u < EB; ++u) t = fmaf(p[u], xv[u][jj], t);
    acc[jj] = fmaf(acc[jj], sc, t);
  }
  m = newm;
}

// single edge with explicit src index + ea array (self-loop / fallback path)
template <int VPL, int C>
__device__ __forceinline__ void process_one(
    int sn, const float* ea,
    const ushort_t* __restrict__ xl, int lane, const float* rv,
    const float (*wreg)[VPL], const float* areg,
    float& m, float& s, float* acc) {
  float xv[VPL];
  loadb<VPL>(xl + (size_t)sn * C + lane * VPL, xv);
  float lg = lrelu_dot<VPL>(xv, rv, wreg, areg, ea);
  float newm = fmaxf(m, lg);
  float sc = __expf(m - newm);
  float p = __expf(lg - newm);
  s = fmaf(s, sc, p);
#pragma unroll
  for (int jj = 0; jj < VPL; ++jj) acc[jj] = fmaf(acc[jj], sc, p * xv[jj]);
  m = newm;
}

// ---------------- fused GATv2 edge+softmax+aggregate: one wave per dst ----------------
template <int C, bool FINAL>
__global__ __launch_bounds__(256) void gat_fused_kernel(
    const int* __restrict__ rowptr,
    const int* __restrict__ srcp, const float* __restrict__ eap,  // permuted (optional)
    const int* __restrict__ perm, const int* __restrict__ src,
    const float* __restrict__ eattr, const float* __restrict__ meanattr,
    int usePerm,
    const ushort_t* __restrict__ xl, const ushort_t* __restrict__ xr,
    const float* __restrict__ We,   // [16, C]
    const float* __restrict__ att,  // [C]
    const float* __restrict__ bias, ushort_t* __restrict__ hout, int N) {
  constexpr int VPL = C / 64;
  constexpr int EB = 4;
  const int lane = threadIdx.x & 63;
  // wave-uniform d so rowptr/srcp/eap accesses become scalar loads
  int d = __builtin_amdgcn_readfirstlane(blockIdx.x * (blockDim.x >> 6) + (threadIdx.x >> 6));
  if (d >= N) return;

  float wreg[16][VPL];
  float areg[VPL];
#pragma unroll
  for (int k = 0; k < 16; ++k)
#pragma unroll
    for (int j = 0; j < VPL; ++j) wreg[k][j] = We[k * C + lane * VPL + j];
#pragma unroll
  for (int j = 0; j < VPL; ++j) areg[j] = att[lane * VPL + j];

  int beg = rowptr[d], end = rowptr[d + 1];
  float rv[VPL];
  loadb<VPL>(xr + (size_t)d * C + lane * VPL, rv);

  float m = -INFINITY, s = 0.f;
  float acc[VPL];
#pragma unroll
  for (int j = 0; j < VPL; ++j) acc[j] = 0.f;

  if (!usePerm) {
    int j = beg;
    for (; j + EB <= end; j += EB)
      process_group<EB, VPL, C>(srcp, eap, j, xl, lane, rv, wreg, areg, m, s, acc);
    for (; j < end; ++j)
      process_group<1, VPL, C>(srcp, eap, j, xl, lane, rv, wreg, areg, m, s, acc);
  } else {
    for (int j = beg; j < end; ++j) {
      int e = perm[j];
      int sn = src[e];
      const float* ap = eattr + (size_t)e * 16;
      float ea[16];
#pragma unroll
      for (int k = 0; k < 16; ++k) ea[k] = ap[k];
      process_one<VPL, C>(sn, ea, xl, lane, rv, wreg, areg, m, s, acc);
    }
  }
  // self loop with mean edge_attr (fill_value='mean'), processed as the last edge
  {
    const float* mp = meanattr + (size_t)d * 16;
    float ea[16];
#pragma unroll
    for (int k = 0; k < 16; ++k) ea[k] = mp[k];
    process_one<VPL, C>(d, ea, xl, lane, rv, wreg, areg, m, s, acc);
  }

  float inv = 1.f / (s + 1e-16f);
  if constexpr (!FINAL) {
    float res[VPL];
#pragma unroll
    for (int j = 0; j < VPL; ++j) {
      float v = acc[j] * inv + bias[lane * VPL + j];
      res[j] = v > 0.f ? v : 0.f;
    }
    storeb<VPL>(hout + (size_t)d * C + lane * VPL, res);
  } else {
    float v[VPL];
#pragma unroll
    for (int j = 0; j < VPL; ++j) v[j] = acc[j] * inv;
#pragma unroll
    for (int j = 0; j < VPL; ++j) {
      v[j] += __shfl_xor(v[j], 16);
      v[j] += __shfl_xor(v[j], 32);
    }
    if (lane < 16) {
      float res[VPL];
#pragma unroll
      for (int j = 0; j < VPL; ++j) {
        float val = 0.25f * v[j] + bias[lane * VPL + j];
        res[j] = val > 0.f ? val : 0.f;
      }
      storeb<VPL>(hout + (size_t)d * 64 + lane * VPL, res);
    }
  }
}

// ---------------- global mean pool: segmented reduction (batch is SORTED) ----------------
__global__ __launch_bounds__(256) void pool_kernel(
    const ushort_t* __restrict__ h3, const int* __restrict__ batch,
    float* __restrict__ gsum, float* __restrict__ gcnt, int N) {
  const int lane = threadIdx.x & 63;
  const int w = blockIdx.x * (blockDim.x >> 6) + (threadIdx.x >> 6);
  const int nw = gridDim.x * (blockDim.x >> 6);
  const int chunk = (N + nw - 1) / nw;
  int i0 = w * chunk;
  int i1 = i0 + chunk; if (i1 > N) i1 = N;
  if (i0 >= i1) return;
  int cur = batch[i0];
  float acc = 0.f;
  int cnt = 0;
  for (int i = i0; i < i1; ++i) {
    int g = batch[i];
    if (g != cur) {
      atomicAdd(&gsum[(size_t)cur * 64 + lane], acc);
      if (lane == 0) atomicAdd(&gcnt[cur], (float)cnt);
      acc = 0.f; cnt = 0; cur = g;
    }
    acc += b2f(h3[(size_t)i * 64 + lane]);
    ++cnt;
  }
  atomicAdd(&gsum[(size_t)cur * 64 + lane], acc);
  if (lane == 0) atomicAdd(&gcnt[cur], (float)cnt);
}

__global__ void final_kernel(const float* __restrict__ gsum, const float* __restrict__ gcnt,
                             const float* __restrict__ Wlin, const float* __restrict__ blin,
                             float* __restrict__ out) {
  int idx = blockIdx.x * blockDim.x + threadIdx.x;
  if (idx >= GG * 16) return;
  int g = idx >> 4, o = idx & 15;
  float c = gcnt[g];
  c = c > 1.f ? c : 1.f;
  float inv = 1.f / c;
  float acc = blin[o];
  for (int f = 0; f < 64; ++f) acc = fmaf(gsum[(size_t)g * 64 + f] * inv, Wlin[f * 16 + o], acc);
  out[idx] = acc;
}

// ---------------- launch ----------------
extern "C" void kernel_launch(void* const* d_in, const int* in_sizes, int n_in,
                              void* d_out, int out_size, void* d_ws, size_t ws_size,
                              hipStream_t stream) {
  (void)in_sizes; (void)n_in; (void)out_size;
  const float* x     = (const float*)d_in[0];
  const int*   eidx  = (const int*)d_in[1];
  const int*   batch = (const int*)d_in[2];
  const float* eattr = (const float*)d_in[3];
  const float* Wl0 = (const float*)d_in[4];  const float* bl0 = (const float*)d_in[5];
  const float* Wr0 = (const float*)d_in[6];  const float* br0 = (const float*)d_in[7];
  const float* We0 = (const float*)d_in[8];  const float* att0 = (const float*)d_in[9];
  const float* bo0 = (const float*)d_in[10];
  const float* Wlh = (const float*)d_in[11]; const float* blh = (const float*)d_in[12];
  const float* Wrh = (const float*)d_in[13]; const float* brh = (const float*)d_in[14];
  const float* Weh = (const float*)d_in[15]; const float* atth = (const float*)d_in[16];
  const float* boh = (const float*)d_in[17];
  const float* Wlf = (const float*)d_in[18]; const float* blf = (const float*)d_in[19];
  const float* Wrf = (const float*)d_in[20]; const float* brf = (const float*)d_in[21];
  const float* Wef = (const float*)d_in[22]; const float* attf = (const float*)d_in[23];
  const float* bof = (const float*)d_in[24];
  const float* Wlin = (const float*)d_in[25]; const float* blin = (const float*)d_in[26];

  const int* src = eidx;
  const int* dst = eidx + EE;

  char* ws = (char*)d_ws;
  size_t off = 0;
  auto take = [&](size_t bytes) -> void* {
    void* p = ws + off;
    off += (bytes + 1023) & ~(size_t)1023;
    return p;
  };
  ushort_t* xl     = (ushort_t*)take((size_t)NN * 256 * 2);
  ushort_t* xr     = (ushort_t*)take((size_t)NN * 256 * 2);
  ushort_t* hb     = (ushort_t*)take((size_t)NN * 128 * 2);   // layer io (bf16)
  ushort_t* xb     = (ushort_t*)take((size_t)NN * 128 * 2);   // x converted
  float* meanattr  = (float*)take((size_t)NN * 16 * 4);
  int* hist        = (int*)take((size_t)NN * 4);
  int* rowptr      = (int*)take((size_t)(NN + 1) * 4);
  int* cursor      = (int*)take((size_t)NN * 4);
  int* perm        = (int*)take((size_t)EE * 4);
  int* bsum        = (int*)take(256);
  int* boff        = (int*)take(256);
  float* gsum      = (float*)take((size_t)GG * 64 * 4);
  float* gcnt      = (float*)take((size_t)GG * 4);
  ushort_t* wtl0   = (ushort_t*)take((size_t)128 * 128 * 2);
  ushort_t* wtr0   = (ushort_t*)take((size_t)128 * 128 * 2);
  ushort_t* wtlh   = (ushort_t*)take((size_t)128 * 128 * 2);
  ushort_t* wtrh   = (ushort_t*)take((size_t)128 * 128 * 2);
  ushort_t* wtlf   = (ushort_t*)take((size_t)256 * 128 * 2);
  ushort_t* wtrf   = (ushort_t*)take((size_t)256 * 128 * 2);
  // optional permuted-edge buffers (sequential reads in the hot loop)
  size_t perm_need = off + (((size_t)EE * 4 + 1023) & ~(size_t)1023)
                   + (((size_t)EE * 16 * 4 + 1023) & ~(size_t)1023);
  int usePerm = (ws_size >= perm_need) ? 0 : 1;  // 0 => permuted srcp/eap path
  int* srcp = nullptr; float* eap = nullptr;
  if (!usePerm) {
    srcp = (int*)take((size_t)EE * 4);
    eap  = (float*)take((size_t)EE * 16 * 4);
  }

  // ---- CSR by dst (dst fixed across layers; rebuilt every call) ----
  hipMemsetAsync(hist, 0, (size_t)NN * 4, stream);
  hipMemsetAsync(gsum, 0, (size_t)GG * 64 * 4, stream);
  hipMemsetAsync(gcnt, 0, (size_t)GG * 4, stream);
  hist_kernel<<<(EE + 255) / 256, 256, 0, stream>>>(dst, hist, EE);
  int nsb = (NN + SCAN_B - 1) / SCAN_B;
  scan_block_kernel<<<nsb, SCAN_B, 0, stream>>>(hist, rowptr + 1, bsum, NN);
  scan_totals_kernel<<<1, 64, 0, stream>>>(bsum, boff, nsb);
  add_offsets_kernel<<<nsb, SCAN_B, 0, stream>>>(rowptr, boff, NN);
  copy_cursor_kernel<<<(NN + 255) / 256, 256, 0, stream>>>(rowptr, cursor, NN);
  scatter_perm_kernel<<<(EE + 255) / 256, 256, 0, stream>>>(dst, cursor, perm, EE);
  if (!usePerm)
    permute_kernel<<<(EE + 255) / 256, 256, 0, stream>>>(perm, src, eattr, srcp, eap, EE);
  mean_attr_kernel<<<(NN * 16 + 255) / 256, 256, 0, stream>>>(rowptr, eap, perm, eattr,
                                                              usePerm, meanattr, NN);
  // weight transpose+convert (tiny) and x conversion
  prep_w_kernel<<<dim3(128, 6), 256, 0, stream>>>(Wl0, wtl0, 128, Wr0, wtr0, 128,
                                                  Wlh, wtlh, 128, Wrh, wtrh, 128,
                                                  Wlf, wtlf, 256, Wrf, wtrf, 256);
  f2b_kernel<<<(NN * 128 / 4 + 255) / 256, 256, 0, stream>>>(x, xb, NN * 128 / 4);

  const int AGG_BLOCKS = (NN + 3) / 4;
  const int GEMM_MB = (NN + 127) / 128;

  // ---- Layer 1 (C=128) ----
  gemm_bt_dual_bf16<<<dim3(GEMM_MB, 2), 256, 0, stream>>>(xb, wtl0, bl0, xl, wtr0, br0, xr, NN, 128);
  gat_fused_kernel<128, false><<<AGG_BLOCKS, 256, 0, stream>>>(
      rowptr, srcp, eap, perm, src, eattr, meanattr, usePerm, xl, xr, We0, att0, bo0, hb, NN);
  // ---- Layer 2 (C=128) ----
  gemm_bt_dual_bf16<<<dim3(GEMM_MB, 2), 256, 0, stream>>>(hb, wtlh, blh, xl, wtrh, brh, xr, NN, 128);
  gat_fused_kernel<128, false><<<AGG_BLOCKS, 256, 0, stream>>>(
      rowptr, srcp, eap, perm, src, eattr, meanattr, usePerm, xl, xr, Weh, atth, boh, hb, NN);
  // ---- Layer 3 (C=256, mean over heads) ----
  gemm_bt_dual_bf16<<<dim3(GEMM_MB, 4), 256, 0, stream>>>(hb, wtlf, blf, xl, wtrf, brf, xr, NN, 256);
  gat_fused_kernel<256, true><<<AGG_BLOCKS, 256, 0, stream>>>(
      rowptr, srcp, eap, perm, src, eattr, meanattr, usePerm, xl, xr, Wef, attf, bof, hb, NN);
  // ---- pool + final linear ----
  pool_kernel<<<128, 256, 0, stream>>>(hb, batch, gsum, gcnt, NN);
  final_kernel<<<4, 256, 0, stream>>>(gsum, gcnt, Wlin, blin, (float*)d_out);
}

// Round 6
// 727.775 us; speedup vs baseline: 2.7973x; 1.0668x over previous
//
#include <hip/hip_runtime.h>
#include <cstddef>

#define NSLOPE 0.2f

constexpr int NN = 50000;
constexpr int EE = 800000;
constexpr int GG = 64;
constexpr int SCAN_B = 1024;

typedef unsigned short ushort_t;
typedef unsigned int uint_t;
typedef __bf16 bhalf;
typedef bhalf bhalf8 __attribute__((ext_vector_type(8)));
typedef float floatx4 __attribute__((ext_vector_type(4)));
typedef _Float16 half_t;
typedef half_t half2_t __attribute__((ext_vector_type(2)));

__device__ __forceinline__ ushort_t f2b(float f) {  // fp32 -> bf16 RNE
  unsigned int u = __float_as_uint(f);
  unsigned int r = (u + 0x7fffu + ((u >> 16) & 1u)) >> 16;
  return (ushort_t)r;
}
__device__ __forceinline__ float b2f(ushort_t b) {
  return __uint_as_float(((unsigned int)b) << 16);
}
__device__ __forceinline__ uint_t packh2(float a, float b) {
  half2_t h = {(half_t)a, (half_t)b};
  return __builtin_bit_cast(uint_t, h);
}
// z += dot2(ea_pair, w_pair) via V_DOT2_F32_F16 (fp32 accumulate)
__device__ __forceinline__ float dot2acc(uint_t ea, half2_t w, float c) {
  half2_t a = __builtin_bit_cast(half2_t, ea);
#if __has_builtin(__builtin_amdgcn_fdot2)
  return __builtin_amdgcn_fdot2(a, w, c, false);
#else
  return c + (float)a.x * (float)w.x + (float)a.y * (float)w.y;
#endif
}

// ---------------- CSR build (dst-sorted edge permutation) ----------------
__global__ void hist_kernel(const int* __restrict__ dst, int* __restrict__ hist, int E) {
  int e = blockIdx.x * blockDim.x + threadIdx.x;
  if (e < E) atomicAdd(&hist[dst[e]], 1);
}

__global__ void scan_block_kernel(const int* __restrict__ in, int* __restrict__ out,
                                  int* __restrict__ bsum, int n) {
  __shared__ int tmp[SCAN_B];
  int gid = blockIdx.x * SCAN_B + threadIdx.x;
  int v = (gid < n) ? in[gid] : 0;
  tmp[threadIdx.x] = v;
  __syncthreads();
  for (int off = 1; off < SCAN_B; off <<= 1) {
    int t = (threadIdx.x >= off) ? tmp[threadIdx.x - off] : 0;
    __syncthreads();
    tmp[threadIdx.x] += t;
    __syncthreads();
  }
  if (gid < n) out[gid] = tmp[threadIdx.x];
  if (threadIdx.x == SCAN_B - 1) bsum[blockIdx.x] = tmp[threadIdx.x];
}

__global__ void scan_totals_kernel(const int* __restrict__ bsum, int* __restrict__ boff, int nb) {
  if (blockIdx.x == 0 && threadIdx.x == 0) {
    int run = 0;
    for (int i = 0; i < nb; ++i) { boff[i] = run; run += bsum[i]; }
  }
}

__global__ void add_offsets_kernel(int* __restrict__ rowptr, const int* __restrict__ boff, int n) {
  int gid = blockIdx.x * SCAN_B + threadIdx.x;
  if (gid == 0) rowptr[0] = 0;
  if (gid < n) rowptr[1 + gid] += boff[blockIdx.x];
}

__global__ void copy_cursor_kernel(const int* __restrict__ rowptr, int* __restrict__ cursor, int n) {
  int i = blockIdx.x * blockDim.x + threadIdx.x;
  if (i < n) cursor[i] = rowptr[i];
}

__global__ void scatter_perm_kernel(const int* __restrict__ dst, int* __restrict__ cursor,
                                    int* __restrict__ perm, int E) {
  int e = blockIdx.x * blockDim.x + threadIdx.x;
  if (e < E) {
    int pos = atomicAdd(&cursor[dst[e]], 1);
    perm[pos] = e;
  }
}

// permute src into dst order; pack edge attrs as f16 pairs eah[E][8]
__global__ void permute_kernel(const int* __restrict__ perm, const int* __restrict__ src,
                               const float* __restrict__ eattr,
                               int* __restrict__ srcp, uint_t* __restrict__ eah, int E) {
  int j = blockIdx.x * blockDim.x + threadIdx.x;
  if (j >= E) return;
  int e = perm[j];
  srcp[j] = src[e];
  const float* a = eattr + (size_t)e * 16;
  uint_t o[8];
#pragma unroll
  for (int k2 = 0; k2 < 8; ++k2) o[k2] = packh2(a[2 * k2], a[2 * k2 + 1]);
  uint4* b = reinterpret_cast<uint4*>(eah + (size_t)j * 8);
  b[0] = make_uint4(o[0], o[1], o[2], o[3]);
  b[1] = make_uint4(o[4], o[5], o[6], o[7]);
}

// per-dst mean edge_attr (self-loop fill_value='mean'), packed f16 pairs [N][8]
__global__ void mean_attr_kernel(const int* __restrict__ rowptr, const uint_t* __restrict__ eah,
                                 const int* __restrict__ perm, const float* __restrict__ eattr,
                                 int usePerm, uint_t* __restrict__ meanattr_h, int N) {
  int idx = blockIdx.x * blockDim.x + threadIdx.x;
  if (idx >= N * 8) return;
  int i = idx >> 3, k2 = idx & 7;
  int beg = rowptr[i], end = rowptr[i + 1];
  float ax = 0.f, ay = 0.f;
  if (!usePerm) {
    for (int j = beg; j < end; ++j) {
      half2_t h = __builtin_bit_cast(half2_t, eah[(size_t)j * 8 + k2]);
      ax += (float)h.x; ay += (float)h.y;
    }
  } else {
    for (int j = beg; j < end; ++j) {
      const float* ap = eattr + (size_t)perm[j] * 16 + k2 * 2;
      ax += ap[0]; ay += ap[1];
    }
  }
  int c = end - beg; if (c < 1) c = 1;
  float inv = 1.f / (float)c;
  meanattr_h[idx] = packh2(ax * inv, ay * inv);
}

// ---------------- bf16 conversion / weight transpose prep ----------------
__global__ void f2b_kernel(const float* __restrict__ in, ushort_t* __restrict__ out, int n4) {
  int i = blockIdx.x * blockDim.x + threadIdx.x;
  if (i >= n4) return;
  float4 v = reinterpret_cast<const float4*>(in)[i];
  ushort4 o = make_ushort4(f2b(v.x), f2b(v.y), f2b(v.z), f2b(v.w));
  reinterpret_cast<ushort4*>(out)[i] = o;
}

// Wt[n][k] = bf16(W[k][n]) for 6 weight matrices, K=128
__global__ void prep_w_kernel(const float* W0, ushort_t* T0, int n0,
                              const float* W1, ushort_t* T1, int n1,
                              const float* W2, ushort_t* T2, int n2,
                              const float* W3, ushort_t* T3, int n3,
                              const float* W4, ushort_t* T4, int n4,
                              const float* W5, ushort_t* T5, int n5) {
  const float* W; ushort_t* T; int Nc;
  switch (blockIdx.y) {
    case 0: W = W0; T = T0; Nc = n0; break;
    case 1: W = W1; T = T1; Nc = n1; break;
    case 2: W = W2; T = T2; Nc = n2; break;
    case 3: W = W3; T = T3; Nc = n3; break;
    case 4: W = W4; T = T4; Nc = n4; break;
    default: W = W5; T = T5; Nc = n5; break;
  }
  int idx = blockIdx.x * blockDim.x + threadIdx.x;
  if (idx >= Nc * 128) return;
  int n = idx >> 7, k = idx & 127;
  T[idx] = f2b(W[(size_t)k * Nc + n]);
}

// -------- dual bf16 MFMA GEMM (B^T layout): Y{0,1} = bf16(Xb @ W{0,1} + b{0,1}) --------
__global__ __launch_bounds__(256) void gemm_bt_dual_bf16(
    const ushort_t* __restrict__ Xb,
    const ushort_t* __restrict__ Wt0, const float* __restrict__ b0, ushort_t* __restrict__ Y0,
    const ushort_t* __restrict__ Wt1, const float* __restrict__ b1, ushort_t* __restrict__ Y1,
    int M, int Nc) {
  constexpr int K = 128, BM = 128, BN = 128, LDT = 136;
  __shared__ ushort_t Als[BM * LDT];
  __shared__ ushort_t Bls[BN * LDT];
  int nb = Nc >> 7;
  int half = blockIdx.y / nb;
  int cb = blockIdx.y % nb;
  const ushort_t* Wt = half ? Wt1 : Wt0;
  const float* bias = half ? b1 : b0;
  ushort_t* Y = half ? Y1 : Y0;
  int r0 = blockIdx.x * BM;
  int col0 = cb * BN;
  int tid = threadIdx.x;
  {
    int rl = tid >> 5;
    int kq = (tid & 31) * 4;
#pragma unroll
    for (int s = 0; s < 16; ++s) {
      int row = rl + s * 8;
      int grow = r0 + row;
      ushort4 v = make_ushort4(0, 0, 0, 0);
      if (grow < M) v = *reinterpret_cast<const ushort4*>(Xb + (size_t)grow * K + kq);
      *reinterpret_cast<ushort4*>(&Als[row * LDT + kq]) = v;
      ushort4 wv = *reinterpret_cast<const ushort4*>(Wt + (size_t)(col0 + row) * K + kq);
      *reinterpret_cast<ushort4*>(&Bls[row * LDT + kq]) = wv;
    }
  }
  __syncthreads();
  int lane = tid & 63;
  int w = tid >> 6;
  int m0 = (w >> 1) * 64;
  int n0 = (w & 1) * 64;
  int rin = lane & 15, quad = lane >> 4;
  floatx4 acc[4][4];
#pragma unroll
  for (int i = 0; i < 4; ++i)
#pragma unroll
    for (int j = 0; j < 4; ++j) acc[i][j] = (floatx4){0.f, 0.f, 0.f, 0.f};
#pragma unroll
  for (int kt = 0; kt < 4; ++kt) {
    int ko = kt * 32 + quad * 8;
    bhalf8 af[4], bf[4];
#pragma unroll
    for (int i = 0; i < 4; ++i)
      af[i] = *reinterpret_cast<const bhalf8*>(&Als[(m0 + i * 16 + rin) * LDT + ko]);
#pragma unroll
    for (int i = 0; i < 4; ++i)
      bf[i] = *reinterpret_cast<const bhalf8*>(&Bls[(n0 + i * 16 + rin) * LDT + ko]);
#pragma unroll
    for (int mi = 0; mi < 4; ++mi)
#pragma unroll
      for (int ni = 0; ni < 4; ++ni)
        acc[mi][ni] = __builtin_amdgcn_mfma_f32_16x16x32_bf16(af[mi], bf[ni], acc[mi][ni], 0, 0, 0);
  }
#pragma unroll
  for (int ni = 0; ni < 4; ++ni) {
    int gcol = col0 + n0 + ni * 16 + rin;
    float bb = bias[gcol];
#pragma unroll
    for (int mi = 0; mi < 4; ++mi) {
      int growb = r0 + m0 + mi * 16 + quad * 4;
#pragma unroll
      for (int r = 0; r < 4; ++r) {
        int grow = growb + r;
        if (grow < M) Y[(size_t)grow * Nc + gcol] = f2b(acc[mi][ni][r] + bb);
      }
    }
  }
}

// ---------------- bf16 vector load/store helpers ----------------
template <int VPL>
__device__ __forceinline__ void loadb(const ushort_t* p, float* v) {
  if constexpr (VPL == 2) {
    ushort2 t = *reinterpret_cast<const ushort2*>(p);
    v[0] = b2f(t.x); v[1] = b2f(t.y);
  } else {
    ushort4 t = *reinterpret_cast<const ushort4*>(p);
    v[0] = b2f(t.x); v[1] = b2f(t.y); v[2] = b2f(t.z); v[3] = b2f(t.w);
  }
}
template <int VPL>
__device__ __forceinline__ void storeb(ushort_t* p, const float* v) {
  if constexpr (VPL == 2) {
    *reinterpret_cast<ushort2*>(p) = make_ushort2(f2b(v[0]), f2b(v[1]));
  } else {
    *reinterpret_cast<ushort4*>(p) = make_ushort4(f2b(v[0]), f2b(v[1]), f2b(v[2]), f2b(v[3]));
  }
}

// per-edge logit: leaky-relu(xl+xr+ea@We) . att (ea@We via 8 dot2 f16 MACs/channel)
template <int VPL>
__device__ __forceinline__ float lrelu_dot(const float* xv, const float* rv,
                                           const half2_t (*wepk)[VPL], const float* areg,
                                           const uint_t* ea) {
  float part = 0.f;
#pragma unroll
  for (int j = 0; j < VPL; ++j) {
    float z = xv[j] + rv[j];
#pragma unroll
    for (int k2 = 0; k2 < 8; ++k2) z = dot2acc(ea[k2], wepk[k2][j], z);
    float zl = fmaxf(z, NSLOPE * z);  // leaky-relu (slope<1)
    part = fmaf(zl, areg[j], part);
  }
  part += __shfl_xor(part, 1);
  part += __shfl_xor(part, 2);
  part += __shfl_xor(part, 4);
  part += __shfl_xor(part, 8);
  return part;
}

// batched online-softmax update over EB edges (ILP over gathers + logit chains,
// one (m,s,acc) rescale per group)
template <int EB, int VPL, int C>
__device__ __forceinline__ void process_group(
    const int* __restrict__ srcp, const uint_t* __restrict__ eah, int j,
    const ushort_t* __restrict__ xl, int lane, const float* rv,
    const half2_t (*wepk)[VPL], const float* areg,
    float& m, float& s, float* acc) {
  int sn[EB];
#pragma unroll
  for (int u = 0; u < EB; ++u) sn[u] = srcp[j + u];
  float xv[EB][VPL];
#pragma unroll
  for (int u = 0; u < EB; ++u) loadb<VPL>(xl + (size_t)sn[u] * C + lane * VPL, xv[u]);
  float lg[EB];
#pragma unroll
  for (int u = 0; u < EB; ++u) {
    const uint_t* ap = eah + (size_t)(j + u) * 8;
    uint_t ea[8];
#pragma unroll
    for (int k2 = 0; k2 < 8; ++k2) ea[k2] = ap[k2];
    lg[u] = lrelu_dot<VPL>(xv[u], rv, wepk, areg, ea);
  }
  float newm = m;
#pragma unroll
  for (int u = 0; u < EB; ++u) newm = fmaxf(newm, lg[u]);
  float sc = __expf(m - newm);  // 0 when m == -inf
  float p[EB], ps = 0.f;
#pragma unroll
  for (int u = 0; u < EB; ++u) { p[u] = __expf(lg[u] - newm); ps += p[u]; }
  s = fmaf(s, sc, ps);
#pragma unroll
  for (int jj = 0; jj < VPL; ++jj) {
    float t = p[0] * xv[0][jj];
#pragma unroll
    for (int u = 1; u < EB; ++u) t = fmaf(p[u], xv[u][jj], t);
    acc[jj] = fmaf(acc[jj], sc, t);
  }
  m = newm;
}

// single edge with explicit src + packed ea pairs (self-loop / fallback path)
template <int VPL, int C>
__device__ __forceinline__ void process_edge(
    int sn, const uint_t* ea,
    const ushort_t* __restrict__ xl, int lane, const float* rv,
    const half2_t (*wepk)[VPL], const float* areg,
    float& m, float& s, float* acc) {
  float xv[VPL];
  loadb<VPL>(xl + (size_t)sn * C + lane * VPL, xv);
  float lg = lrelu_dot<VPL>(xv, rv, wepk, areg, ea);
  float newm = fmaxf(m, lg);
  float sc = __expf(m - newm);
  float p = __expf(lg - newm);
  s = fmaf(s, sc, p);
#pragma unroll
  for (int jj = 0; jj < VPL; ++jj) acc[jj] = fmaf(acc[jj], sc, p * xv[jj]);
  m = newm;
}

// ---------------- fused GATv2 edge+softmax+aggregate: one wave per dst ----------------
template <int C, bool FINAL>
__global__ __launch_bounds__(256) void gat_fused_kernel(
    const int* __restrict__ rowptr,
    const int* __restrict__ srcp, const uint_t* __restrict__ eah,  // permuted (optional)
    const int* __restrict__ perm, const int* __restrict__ src,
    const float* __restrict__ eattr, const uint_t* __restrict__ meanattr_h,
    int usePerm,
    const ushort_t* __restrict__ xl, const ushort_t* __restrict__ xr,
    const float* __restrict__ We,   // [16, C] fp32 (packed to f16 pairs in regs)
    const float* __restrict__ att,  // [C]
    const float* __restrict__ bias, ushort_t* __restrict__ hout, int N) {
  constexpr int VPL = C / 64;
  const int lane = threadIdx.x & 63;
  int d = __builtin_amdgcn_readfirstlane(blockIdx.x * (blockDim.x >> 6) + (threadIdx.x >> 6));
  if (d >= N) return;

  half2_t wepk[8][VPL];  // We k-pairs per channel: half the regs of fp32, 2 MACs/dot2
  float areg[VPL];
#pragma unroll
  for (int k2 = 0; k2 < 8; ++k2)
#pragma unroll
    for (int j = 0; j < VPL; ++j) {
      int ch = lane * VPL + j;
      wepk[k2][j] = (half2_t){(half_t)We[(2 * k2) * C + ch], (half_t)We[(2 * k2 + 1) * C + ch]};
    }
#pragma unroll
  for (int j = 0; j < VPL; ++j) areg[j] = att[lane * VPL + j];

  int beg = rowptr[d], end = rowptr[d + 1];
  float rv[VPL];
  loadb<VPL>(xr + (size_t)d * C + lane * VPL, rv);

  float m = -INFINITY, s = 0.f;
  float acc[VPL];
#pragma unroll
  for (int j = 0; j < VPL; ++j) acc[j] = 0.f;

  if (!usePerm) {
    int j = beg;
    if constexpr (C == 128) {
      for (; j + 8 <= end; j += 8)
        process_group<8, VPL, C>(srcp, eah, j, xl, lane, rv, wepk, areg, m, s, acc);
    }
    for (; j + 4 <= end; j += 4)
      process_group<4, VPL, C>(srcp, eah, j, xl, lane, rv, wepk, areg, m, s, acc);
    for (; j + 2 <= end; j += 2)
      process_group<2, VPL, C>(srcp, eah, j, xl, lane, rv, wepk, areg, m, s, acc);
    for (; j < end; ++j)
      process_group<1, VPL, C>(srcp, eah, j, xl, lane, rv, wepk, areg, m, s, acc);
  } else {
    for (int j = beg; j < end; ++j) {
      int e = perm[j];
      int sn = src[e];
      const float* ap = eattr + (size_t)e * 16;
      uint_t ea[8];
#pragma unroll
      for (int k2 = 0; k2 < 8; ++k2) ea[k2] = packh2(ap[2 * k2], ap[2 * k2 + 1]);
      process_edge<VPL, C>(sn, ea, xl, lane, rv, wepk, areg, m, s, acc);
    }
  }
  // self loop with mean edge_attr (fill_value='mean'), processed as the last edge
  {
    const uint_t* mp = meanattr_h + (size_t)d * 8;
    uint_t ea[8];
#pragma unroll
    for (int k2 = 0; k2 < 8; ++k2) ea[k2] = mp[k2];
    process_edge<VPL, C>(d, ea, xl, lane, rv, wepk, areg, m, s, acc);
  }

  float inv = 1.f / (s + 1e-16f);
  if constexpr (!FINAL) {
    float res[VPL];
#pragma unroll
    for (int j = 0; j < VPL; ++j) {
      float v = acc[j] * inv + bias[lane * VPL + j];
      res[j] = v > 0.f ? v : 0.f;
    }
    storeb<VPL>(hout + (size_t)d * C + lane * VPL, res);
  } else {
    float v[VPL];
#pragma unroll
    for (int j = 0; j < VPL; ++j) v[j] = acc[j] * inv;
#pragma unroll
    for (int j = 0; j < VPL; ++j) {
      v[j] += __shfl_xor(v[j], 16);
      v[j] += __shfl_xor(v[j], 32);
    }
    if (lane < 16) {
      float res[VPL];
#pragma unroll
      for (int j = 0; j < VPL; ++j) {
        float val = 0.25f * v[j] + bias[lane * VPL + j];
        res[j] = val > 0.f ? val : 0.f;
      }
      storeb<VPL>(hout + (size_t)d * 64 + lane * VPL, res);
    }
  }
}

// ---------------- global mean pool: segmented reduction (batch is SORTED) ----------------
__global__ __launch_bounds__(256) void pool_kernel(
    const ushort_t* __restrict__ h3, const int* __restrict__ batch,
    float* __restrict__ gsum, float* __restrict__ gcnt, int N) {
  const int lane = threadIdx.x & 63;
  const int w = blockIdx.x * (blockDim.x >> 6) + (threadIdx.x >> 6);
  const int nw = gridDim.x * (blockDim.x >> 6);
  const int chunk = (N + nw - 1) / nw;
  int i0 = w * chunk;
  int i1 = i0 + chunk; if (i1 > N) i1 = N;
  if (i0 >= i1) return;
  int cur = batch[i0];
  float acc = 0.f;
  int cnt = 0;
  for (int i = i0; i < i1; ++i) {
    int g = batch[i];
    if (g != cur) {
      atomicAdd(&gsum[(size_t)cur * 64 + lane], acc);
      if (lane == 0) atomicAdd(&gcnt[cur], (float)cnt);
      acc = 0.f; cnt = 0; cur = g;
    }
    acc += b2f(h3[(size_t)i * 64 + lane]);
    ++cnt;
  }
  atomicAdd(&gsum[(size_t)cur * 64 + lane], acc);
  if (lane == 0) atomicAdd(&gcnt[cur], (float)cnt);
}

__global__ void final_kernel(const float* __restrict__ gsum, const float* __restrict__ gcnt,
                             const float* __restrict__ Wlin, const float* __restrict__ blin,
                             float* __restrict__ out) {
  int idx = blockIdx.x * blockDim.x + threadIdx.x;
  if (idx >= GG * 16) return;
  int g = idx >> 4, o = idx & 15;
  float c = gcnt[g];
  c = c > 1.f ? c : 1.f;
  float inv = 1.f / c;
  float acc = blin[o];
  for (int f = 0; f < 64; ++f) acc = fmaf(gsum[(size_t)g * 64 + f] * inv, Wlin[f * 16 + o], acc);
  out[idx] = acc;
}

// ---------------- launch ----------------
extern "C" void kernel_launch(void* const* d_in, const int* in_sizes, int n_in,
                              void* d_out, int out_size, void* d_ws, size_t ws_size,
                              hipStream_t stream) {
  (void)in_sizes; (void)n_in; (void)out_size;
  const float* x     = (const float*)d_in[0];
  const int*   eidx  = (const int*)d_in[1];
  const int*   batch = (const int*)d_in[2];
  const float* eattr = (const float*)d_in[3];
  const float* Wl0 = (const float*)d_in[4];  const float* bl0 = (const float*)d_in[5];
  const float* Wr0 = (const float*)d_in[6];  const float* br0 = (const float*)d_in[7];
  const float* We0 = (const float*)d_in[8];  const float* att0 = (const float*)d_in[9];
  const float* bo0 = (const float*)d_in[10];
  const float* Wlh = (const float*)d_in[11]; const float* blh = (const float*)d_in[12];
  const float* Wrh = (const float*)d_in[13]; const float* brh = (const float*)d_in[14];
  const float* Weh = (const float*)d_in[15]; const float* atth = (const float*)d_in[16];
  const float* boh = (const float*)d_in[17];
  const float* Wlf = (const float*)d_in[18]; const float* blf = (const float*)d_in[19];
  const float* Wrf = (const float*)d_in[20]; const float* brf = (const float*)d_in[21];
  const float* Wef = (const float*)d_in[22]; const float* attf = (const float*)d_in[23];
  const float* bof = (const float*)d_in[24];
  const float* Wlin = (const float*)d_in[25]; const float* blin = (const float*)d_in[26];

  const int* src = eidx;
  const int* dst = eidx + EE;

  char* ws = (char*)d_ws;
  size_t off = 0;
  auto take = [&](size_t bytes) -> void* {
    void* p = ws + off;
    off += (bytes + 1023) & ~(size_t)1023;
    return p;
  };
  ushort_t* xl     = (ushort_t*)take((size_t)NN * 256 * 2);
  ushort_t* xr     = (ushort_t*)take((size_t)NN * 256 * 2);
  ushort_t* hb     = (ushort_t*)take((size_t)NN * 128 * 2);   // layer io (bf16)
  ushort_t* xb     = (ushort_t*)take((size_t)NN * 128 * 2);   // x converted
  uint_t* meanattr_h = (uint_t*)take((size_t)NN * 8 * 4);     // f16 pairs
  int* hist        = (int*)take((size_t)NN * 4);
  int* rowptr      = (int*)take((size_t)(NN + 1) * 4);
  int* cursor      = (int*)take((size_t)NN * 4);
  int* perm        = (int*)take((size_t)EE * 4);
  int* bsum        = (int*)take(256);
  int* boff        = (int*)take(256);
  float* gsum      = (float*)take((size_t)GG * 64 * 4);
  float* gcnt      = (float*)take((size_t)GG * 4);
  ushort_t* wtl0   = (ushort_t*)take((size_t)128 * 128 * 2);
  ushort_t* wtr0   = (ushort_t*)take((size_t)128 * 128 * 2);
  ushort_t* wtlh   = (ushort_t*)take((size_t)128 * 128 * 2);
  ushort_t* wtrh   = (ushort_t*)take((size_t)128 * 128 * 2);
  ushort_t* wtlf   = (ushort_t*)take((size_t)256 * 128 * 2);
  ushort_t* wtrf   = (ushort_t*)take((size_t)256 * 128 * 2);
  // optional permuted-edge buffers (sequential reads in the hot loop)
  size_t perm_need = off + (((size_t)EE * 4 + 1023) & ~(size_t)1023)
                   + (((size_t)EE * 8 * 4 + 1023) & ~(size_t)1023);
  int usePerm = (ws_size >= perm_need) ? 0 : 1;  // 0 => permuted srcp/eah path
  int* srcp = nullptr; uint_t* eah = nullptr;
  if (!usePerm) {
    srcp = (int*)take((size_t)EE * 4);
    eah  = (uint_t*)take((size_t)EE * 8 * 4);
  }

  // ---- CSR by dst (dst fixed across layers; rebuilt every call) ----
  hipMemsetAsync(hist, 0, (size_t)NN * 4, stream);
  hipMemsetAsync(gsum, 0, (size_t)GG * 64 * 4, stream);
  hipMemsetAsync(gcnt, 0, (size_t)GG * 4, stream);
  hist_kernel<<<(EE + 255) / 256, 256, 0, stream>>>(dst, hist, EE);
  int nsb = (NN + SCAN_B - 1) / SCAN_B;
  scan_block_kernel<<<nsb, SCAN_B, 0, stream>>>(hist, rowptr + 1, bsum, NN);
  scan_totals_kernel<<<1, 64, 0, stream>>>(bsum, boff, nsb);
  add_offsets_kernel<<<nsb, SCAN_B, 0, stream>>>(rowptr, boff, NN);
  copy_cursor_kernel<<<(NN + 255) / 256, 256, 0, stream>>>(rowptr, cursor, NN);
  scatter_perm_kernel<<<(EE + 255) / 256, 256, 0, stream>>>(dst, cursor, perm, EE);
  if (!usePerm)
    permute_kernel<<<(EE + 255) / 256, 256, 0, stream>>>(perm, src, eattr, srcp, eah, EE);
  mean_attr_kernel<<<(NN * 8 + 255) / 256, 256, 0, stream>>>(rowptr, eah, perm, eattr,
                                                             usePerm, meanattr_h, NN);
  // weight transpose+convert (tiny) and x conversion
  prep_w_kernel<<<dim3(128, 6), 256, 0, stream>>>(Wl0, wtl0, 128, Wr0, wtr0, 128,
                                                  Wlh, wtlh, 128, Wrh, wtrh, 128,
                                                  Wlf, wtlf, 256, Wrf, wtrf, 256);
  f2b_kernel<<<(NN * 128 / 4 + 255) / 256, 256, 0, stream>>>(x, xb, NN * 128 / 4);

  const int AGG_BLOCKS = (NN + 3) / 4;
  const int GEMM_MB = (NN + 127) / 128;

  // ---- Layer 1 (C=128) ----
  gemm_bt_dual_bf16<<<dim3(GEMM_MB, 2), 256, 0, stream>>>(xb, wtl0, bl0, xl, wtr0, br0, xr, NN, 128);
  gat_fused_kernel<128, false><<<AGG_BLOCKS, 256, 0, stream>>>(
      rowptr, srcp, eah, perm, src, eattr, meanattr_h, usePerm, xl, xr, We0, att0, bo0, hb, NN);
  // ---- Layer 2 (C=128) ----
  gemm_bt_dual_bf16<<<dim3(GEMM_MB, 2), 256, 0, stream>>>(hb, wtlh, blh, xl, wtrh, brh, xr, NN, 128);
  gat_fused_kernel<128, false><<<AGG_BLOCKS, 256, 0, stream>>>(
      rowptr, srcp, eah, perm, src, eattr, meanattr_h, usePerm, xl, xr, Weh, atth, boh, hb, NN);
  // ---- Layer 3 (C=256, mean over heads) ----
  gemm_bt_dual_bf16<<<dim3(GEMM_MB, 4), 256, 0, stream>>>(hb, wtlf, blf, xl, wtrf, brf, xr, NN, 256);
  gat_fused_kernel<256, true><<<AGG_BLOCKS, 256, 0, stream>>>(
      rowptr, srcp, eah, perm, src, eattr, meanattr_h, usePerm, xl, xr, Wef, attf, bof, hb, NN);
  // ---- pool + final linear ----
  pool_kernel<<<128, 256, 0, stream>>>(hb, batch, gsum, gcnt, NN);
  final_kernel<<<4, 256, 0, stream>>>(gsum, gcnt, Wlin, blin, (float*)d_out);
}